// Round 16
// baseline (350.235 us; speedup 1.0000x reference)
//
#include <hip/hip_runtime.h>
#include <math.h>

#define CDIM 256
#define KDIM 1024
#define TOPK 8
#define MROWS 32
#define NELEM 16777216
#define L2E 1.4426950408889634f

typedef unsigned short u16;
typedef unsigned int u32;
typedef __attribute__((ext_vector_type(8))) short s16x8;
typedef __attribute__((ext_vector_type(8))) __bf16 b16x8;
typedef __attribute__((ext_vector_type(16))) float f32x16;
typedef __attribute__((ext_vector_type(4))) float f32x4;

#define ZERO16 {0.f,0.f,0.f,0.f,0.f,0.f,0.f,0.f,0.f,0.f,0.f,0.f,0.f,0.f,0.f,0.f}

// ws layout (bytes)
#define WS_COUNTS 64
#define WS_DN     4608
#define WS_B2     8704
#define WS_WH     16384                     // WhT: fragment-transposed, 512KB
#define WS_DH     (WS_WH + 524288)          // DhT: fragment-transposed, 512KB
#define WS_SEL    1064960                   // int[65536*8]   = 2 MB
#define WS_SELP   (WS_SEL + 2097152)        // float[65536*8] = 2 MB
#define WS_LR     (WS_SELP + 2097152)       // float2[8192]   = 64 KB

// K1 smem layout (bytes); overlays on xl/b2/dn after the main loop.
// xh/xl FRAGMENT-LINEAR: fragment f of row r at byte (f*32+r)*16, dims [8f,8f+8)
#define SM_XH   0        // 16K (LIVE through p-recompute)
#define SM_XL   16384    // 16K
#define SM_B2   32768    // 4K
#define SM_DN   36864    // 4K
#define SM_TOT  40960
#define SM_PD   16384    // 8K over xl
#define SM_PI   24576    // 8K over xl
#define SM_PM   32768    // 1K over b2
#define SM_PS   33792    // 1K over b2
#define SM_SELI 36864    // 1K over dn
#define SM_SELM 37888    // 128B over dn
#define SM_SELS 38016    // 128B over dn

__device__ __forceinline__ u16 f2bf(float f) {
    u32 u = __builtin_bit_cast(u32, f);
    u += 0x7FFFu + ((u >> 16) & 1u);
    return (u16)(u >> 16);
}
__device__ __forceinline__ float bf2f(u16 h) {
    return __builtin_bit_cast(float, ((u32)h) << 16);
}
__device__ __forceinline__ float hi2f(u32 u) {
    return __builtin_bit_cast(float, u & 0xFFFF0000u);
}
__device__ __forceinline__ f32x16 mfma16(s16x8 a, s16x8 b, f32x16 c) {
    return __builtin_amdgcn_mfma_f32_32x32x16_bf16(
        __builtin_bit_cast(b16x8, a), __builtin_bit_cast(b16x8, b), c, 0, 0, 0);
}
__device__ __forceinline__ u32 mono(float f) {
    u32 u = __builtin_bit_cast(u32, f);
    int m = (int)u >> 31;
    return u ^ (u32)(m | (int)0x80000000);
}
__device__ __forceinline__ float unmono(u32 v) {
    int m = (int)v >> 31;
    return __builtin_bit_cast(float, v ^ (u32)((int)0x80000000 | ~m));
}

// packed sorted-ascending insert: v_min_u32 + v_max_u32 per position
#define INSP(HK, PK) { u32 c_ = (PK); \
    _Pragma("unroll") \
    for (int p_ = 0; p_ < 8; ++p_) { \
        u32 lo_ = min(c_, HK[p_]); \
        u32 hi_ = max(c_, HK[p_]); \
        HK[p_] = lo_; c_ = hi_; } }

#define CE(HD, HX, A, B) { \
    bool sw_ = (HD[B] < HD[A]) || (HD[B] == HD[A] && HX[B] < HX[A]); \
    if (sw_) { float td_ = HD[A]; HD[A] = HD[B]; HD[B] = td_; \
               int ti_ = HX[A]; HX[A] = HX[B]; HX[B] = ti_; } }

#define MERGE8(HD, HX, OD, OI) { \
    _Pragma("unroll") \
    for (int j_ = 0; j_ < 8; ++j_) { \
        float bd_ = OD[7 - j_]; int bi_ = OI[7 - j_]; \
        if (bd_ < HD[j_] || (bd_ == HD[j_] && bi_ < HX[j_])) { \
            HD[j_] = bd_; HX[j_] = bi_; } } \
    CE(HD,HX,0,4) CE(HD,HX,1,5) CE(HD,HX,2,6) CE(HD,HX,3,7) \
    CE(HD,HX,0,2) CE(HD,HX,1,3) CE(HD,HX,4,6) CE(HD,HX,5,7) \
    CE(HD,HX,0,1) CE(HD,HX,2,3) CE(HD,HX,4,5) CE(HD,HX,6,7) }

#define SMAX_TILE(ACC, MM, SS) { \
    float lv_[16]; \
    _Pragma("unroll") \
    for (int rg_ = 0; rg_ < 4; ++rg_) { \
        lv_[4*rg_+0] = ACC[4*rg_+0] + bv4[rg_].x; \
        lv_[4*rg_+1] = ACC[4*rg_+1] + bv4[rg_].y; \
        lv_[4*rg_+2] = ACC[4*rg_+2] + bv4[rg_].z; \
        lv_[4*rg_+3] = ACC[4*rg_+3] + bv4[rg_].w; } \
    float x0_ = fmaxf(lv_[0],lv_[1]),  x1_ = fmaxf(lv_[2],lv_[3]); \
    float x2_ = fmaxf(lv_[4],lv_[5]),  x3_ = fmaxf(lv_[6],lv_[7]); \
    float x4_ = fmaxf(lv_[8],lv_[9]),  x5_ = fmaxf(lv_[10],lv_[11]); \
    float x6_ = fmaxf(lv_[12],lv_[13]), x7_ = fmaxf(lv_[14],lv_[15]); \
    x0_ = fmaxf(x0_,x1_); x2_ = fmaxf(x2_,x3_); \
    x4_ = fmaxf(x4_,x5_); x6_ = fmaxf(x6_,x7_); \
    float mn_ = fmaxf(fmaxf(fmaxf(x0_,x2_), fmaxf(x4_,x6_)), MM); \
    float e0_ = exp2f(lv_[0]-mn_) + exp2f(lv_[1]-mn_); \
    float e1_ = exp2f(lv_[2]-mn_) + exp2f(lv_[3]-mn_); \
    float e2_ = exp2f(lv_[4]-mn_) + exp2f(lv_[5]-mn_); \
    float e3_ = exp2f(lv_[6]-mn_) + exp2f(lv_[7]-mn_); \
    float e4_ = exp2f(lv_[8]-mn_) + exp2f(lv_[9]-mn_); \
    float e5_ = exp2f(lv_[10]-mn_) + exp2f(lv_[11]-mn_); \
    float e6_ = exp2f(lv_[12]-mn_) + exp2f(lv_[13]-mn_); \
    float e7_ = exp2f(lv_[14]-mn_) + exp2f(lv_[15]-mn_); \
    float sa_ = ((e0_+e1_) + (e2_+e3_)) + ((e4_+e5_) + (e6_+e7_)); \
    SS = SS * exp2f(MM - mn_) + sa_; MM = mn_; }

// ---------------- prepass: bf16 splits into FRAGMENT-TRANSPOSED layout ------
__global__ __launch_bounds__(256)
void dl_prep(const float* __restrict__ Wm, const float* __restrict__ dict,
             const float* __restrict__ bv,
             u16* __restrict__ WhT, u16* __restrict__ DhT,
             float* __restrict__ dn, float* __restrict__ b2)
{
    __shared__ float red[4];
    const int k = blockIdx.x, c = threadIdx.x;
    const size_t idx = ((size_t)k << 8) + c;
    const size_t dst = ((((size_t)(k >> 5) * 16 + (c >> 4)) * 64)
                        + (((c >> 3) & 1) << 5) + (k & 31)) * 8 + (c & 7);
    WhT[dst] = f2bf(Wm[idx] * L2E);
    float d = dict[idx];
    DhT[dst] = f2bf(-2.0f * d);
    float sq = d * d;
    #pragma unroll
    for (int off = 32; off; off >>= 1) sq += __shfl_down(sq, off);
    if ((c & 63) == 0) red[c >> 6] = sq;
    __syncthreads();
    if (c == 0) { dn[k] = red[0] + red[1] + red[2] + red[3]; b2[k] = bv[k] * L2E; }
}

// ---------------- K1: selection + probabilities (R15 + 8 waves/SIMD cap) ----
__global__ __launch_bounds__(512, 8)
void dl_main(const float* __restrict__ x, const float* __restrict__ Wm,
             const float* __restrict__ bv, const u16* __restrict__ WhT,
             const u16* __restrict__ DhT, const float* __restrict__ dnp,
             const float* __restrict__ b2g,
             int* __restrict__ ws_sel, float* __restrict__ ws_selp)
{
    __shared__ __align__(16) char smem[SM_TOT];
    u16*   xh   = (u16*)(smem + SM_XH);
    u16*   xl   = (u16*)(smem + SM_XL);
    float* b2_s = (float*)(smem + SM_B2);
    float* dn_s = (float*)(smem + SM_DN);
    float* pd   = (float*)(smem + SM_PD);
    int*   pi   = (int*)(smem + SM_PI);
    float* pm   = (float*)(smem + SM_PM);
    float* ps   = (float*)(smem + SM_PS);
    int*   seli = (int*)(smem + SM_SELI);
    float* selm = (float*)(smem + SM_SELM);
    float* sels = (float*)(smem + SM_SELS);

    const int t = threadIdx.x;
    const int lane = t & 63;
    const int wid = t >> 6;
    const int n0 = blockIdx.x * MROWS;

    // ---- stage x -> bf16 hi/lo in FRAGMENT-LINEAR layout (write addr = t*16)
    {
        const int r = t & 31;
        const float* xb = x + ((size_t)(n0 >> 12) << 20) + (n0 & 4095) + r;
        #pragma unroll
        for (int gg = 0; gg < 2; ++gg) {
            const int f = (t >> 5) + gg * 16;     // fragment id, dims [8f,8f+8)
            const int c0 = f * 8;
            u32 hw[4], lw[4];
            #pragma unroll
            for (int i = 0; i < 8; i += 2) {
                float a0 = xb[(size_t)(c0 + i) << 12];
                float a1 = xb[(size_t)(c0 + i + 1) << 12];
                u16 h0 = f2bf(a0), h1 = f2bf(a1);
                u16 e0 = f2bf(a0 - bf2f(h0)), e1 = f2bf(a1 - bf2f(h1));
                hw[i >> 1] = (u32)h0 | ((u32)h1 << 16);
                lw[i >> 1] = (u32)e0 | ((u32)e1 << 16);
            }
            const int byte = (f * 32 + r) * 16;   // == (t + gg*512)*16, linear
            *(uint4*)((char*)xh + byte) = make_uint4(hw[0], hw[1], hw[2], hw[3]);
            *(uint4*)((char*)xl + byte) = make_uint4(lw[0], lw[1], lw[2], lw[3]);
        }
        b2_s[t] = b2g[t];  b2_s[512 + t] = b2g[512 + t];
        dn_s[t] = dnp[t];  dn_s[512 + t] = dnp[512 + t];
    }
    __syncthreads();

    const int arow = lane & 31, hl = lane >> 5;

    float m0 = -INFINITY, s0 = 0.f;
    u32 hk0[TOPK];
    #pragma unroll
    for (int j = 0; j < TOPK; ++j) hk0[j] = 0xFFFFFFFFu;

    // ---- barrier-free main loop: 4 chunks of 256 atoms
    #pragma unroll 1
    for (int ck = 0; ck < 4; ++ck) {
        const int ab = ck * 8 + wid;          // atom block: atoms [ab*32, +32)
        const u16* Wp = WhT + ((size_t)ab << 13) + (lane << 3);
        const u16* Dp = DhT + ((size_t)ab << 13) + (lane << 3);
        const int cb = (ck << 8) + (wid << 5) + (hl << 2);

        // L phase: logits from x_hi; atom load = contiguous 1KB per instr
        f32x16 accL = ZERO16;
        __builtin_amdgcn_s_setprio(1);
        #pragma unroll 8
        for (int kst = 0; kst < 16; ++kst) {
            int bo = kst * 1024 + lane * 16;
            s16x8 aw = *(const s16x8*)(Wp + kst * 512);
            s16x8 bh = *(const s16x8*)((const char*)xh + bo);
            accL = mfma16(aw, bh, accL);
        }
        __builtin_amdgcn_s_setprio(0);

        float4 bv4[4];
        #pragma unroll
        for (int rg = 0; rg < 4; ++rg)
            bv4[rg] = *(const float4*)(b2_s + cb + rg * 8);
        SMAX_TILE(accL, m0, s0)

        // D phase: -2 x.d_hi with full-x (hi+lo) precision
        f32x16 accD = ZERO16;
        __builtin_amdgcn_s_setprio(1);
        #pragma unroll 8
        for (int kst = 0; kst < 16; ++kst) {
            int bo = kst * 1024 + lane * 16;
            s16x8 adh = *(const s16x8*)(Dp + kst * 512);
            s16x8 bh = *(const s16x8*)((const char*)xh + bo);
            s16x8 bl = *(const s16x8*)((const char*)xl + bo);
            accD = mfma16(adh, bh, accD);
            accD = mfma16(adh, bl, accD);
        }
        __builtin_amdgcn_s_setprio(0);

        float4 n44[4];
        #pragma unroll
        for (int rg = 0; rg < 4; ++rg)
            n44[rg] = *(const float4*)(dn_s + cb + rg * 8);
        const u32 ob = (u32)(ck << 4);
        #pragma unroll
        for (int rg = 0; rg < 4; ++rg) {
            u32 o0 = ob + rg * 4;
            float d0 = n44[rg].x + accD[4*rg+0];
            float d1 = n44[rg].y + accD[4*rg+1];
            float d2 = n44[rg].z + accD[4*rg+2];
            float d3 = n44[rg].w + accD[4*rg+3];
            INSP(hk0, (mono(d0) & ~63u) | (o0 + 0))
            INSP(hk0, (mono(d1) & ~63u) | (o0 + 1))
            INSP(hk0, (mono(d2) & ~63u) | (o0 + 2))
            INSP(hk0, (mono(d3) & ~63u) | (o0 + 3))
        }
    }

    // ---- decode packed keys -> (dist, global atom idx)
    float hd0[TOPK];
    int hix0[TOPK];
    #pragma unroll
    for (int j = 0; j < TOPK; ++j) {
        u32 v = hk0[j]; int o = (int)(v & 63u);
        hd0[j] = unmono(v & ~63u);
        hix0[j] = ((o >> 4) << 8) + (wid << 5) + (((o >> 2) & 3) << 3) + (hl << 2) + (o & 3);
    }

    // ---- intra-wave merge (lane n <-> n+32)
    {
        float mo = __shfl_xor(m0, 32), so = __shfl_xor(s0, 32);
        float mn = fmaxf(m0, mo);
        s0 = s0 * exp2f(m0 - mn) + so * exp2f(mo - mn);
        m0 = mn;
        float od[TOPK]; int oi[TOPK];
        #pragma unroll
        for (int j = 0; j < TOPK; ++j) {
            od[j] = __shfl_xor(hd0[j], 32); oi[j] = __shfl_xor(hix0[j], 32);
        }
        MERGE8(hd0, hix0, od, oi)
    }

    // ---- publish the 8 wave-lists per row (overlay on dead xl/b2)
    __syncthreads();
    if (lane < 32) {
        const int base = arow * 64 + wid * 8;
        #pragma unroll
        for (int j = 0; j < TOPK; ++j) { pd[base + j] = hd0[j]; pi[base + j] = hix0[j]; }
        pm[arow * 8 + wid] = m0; ps[arow * 8 + wid] = s0;
    }
    __syncthreads();

    // ---- final merge (8 threads/row) -> seli/selm/sels (LDS) + ws_sel
    if (t < 256) {
        const int row = t >> 3, src = t & 7;
        float hd[TOPK]; int hix[TOPK];
        #pragma unroll
        for (int j = 0; j < TOPK; ++j) {
            hd[j] = pd[row * 64 + src * 8 + j];
            hix[j] = pi[row * 64 + src * 8 + j];
        }
        float m = pm[row * 8 + src], s = ps[row * 8 + src];
        #pragma unroll
        for (int k = 1; k <= 4; k <<= 1) {
            float mo = __shfl_xor(m, k), so = __shfl_xor(s, k);
            float mn = fmaxf(m, mo);
            s = s * exp2f(m - mn) + so * exp2f(mo - mn);
            m = mn;
            float od[TOPK]; int oi[TOPK];
            #pragma unroll
            for (int j = 0; j < TOPK; ++j) {
                od[j] = __shfl_xor(hd[j], k); oi[j] = __shfl_xor(hix[j], k);
            }
            MERGE8(hd, hix, od, oi)
        }
        if (src == 0) {
            size_t n = (size_t)(n0 + row);
            selm[row] = m;
            sels[row] = 1.0f / s;
            #pragma unroll
            for (int j = 0; j < TOPK; ++j) seli[row * 8 + j] = hix[j];
            *(int4*)(ws_sel + n * 8)     = make_int4(hix[0], hix[1], hix[2], hix[3]);
            *(int4*)(ws_sel + n * 8 + 4) = make_int4(hix[4], hix[5], hix[6], hix[7]);
        }
    }
    __syncthreads();

    // ---- recompute winner logits from LDS xh (true x_flat rows) + fp32 W, b
    {
        const int row = t >> 4, j = (t >> 1) & 7, half = t & 1;
        const int idxw = seli[row * 8 + j];
        const float4* wp = (const float4*)(Wm + ((size_t)idxw << 8)) + half * 32;
        float ax = 0.f, ay = 0.f, az = 0.f, aw2 = 0.f;
        #pragma unroll 8
        for (int i = 0; i < 16; ++i) {
            const int byte = ((half * 16 + i) * 32 + row) * 16;  // fragment-linear
            uint4 H = *(const uint4*)((const char*)xh + byte);
            float4 w0 = wp[i * 2], w1 = wp[i * 2 + 1];
            ax += bf2f((u16)H.x) * w0.x; ay += hi2f(H.x) * w0.y;
            az += bf2f((u16)H.y) * w0.z; aw2 += hi2f(H.y) * w0.w;
            ax += bf2f((u16)H.z) * w1.x; ay += hi2f(H.z) * w1.y;
            az += bf2f((u16)H.w) * w1.z; aw2 += hi2f(H.w) * w1.w;
        }
        float a = (ax + ay) + (az + aw2);
        a += __shfl_xor(a, 1);
        if (half == 0) {
            float p = exp2f((a + bv[idxw]) * L2E - selm[row]) * sels[row];
            ws_selp[(size_t)(n0 + row) * 8 + j] = p;
        }
    }
}

// ---------------- K2c: counts via LDS histogram (skew-proof) ----------------
__global__ __launch_bounds__(256)
void dl_count(const int* __restrict__ ws_sel, int* __restrict__ counts)
{
    __shared__ int hist[KDIM];
    const int t = threadIdx.x;
    #pragma unroll
    for (int i = 0; i < 4; ++i) hist[t + i * 256] = 0;
    __syncthreads();
    const int4* src = (const int4*)(ws_sel + (size_t)blockIdx.x * 8192);
    #pragma unroll
    for (int i = 0; i < 8; ++i) {
        int4 v = src[(size_t)i * 256 + t];
        atomicAdd(&hist[v.x], 1); atomicAdd(&hist[v.y], 1);
        atomicAdd(&hist[v.z], 1); atomicAdd(&hist[v.w], 1);
    }
    __syncthreads();
    #pragma unroll
    for (int i = 0; i < 4; ++i) {
        int k = t + i * 256;
        int c = hist[k];
        if (c) atomicAdd(&counts[k], c);
    }
}

// ---------------- K2: merged tail — rep compose + recon + MSE + partials ----
__global__ __launch_bounds__(256, 8)
void dl_tail(const float* __restrict__ x, const float* __restrict__ dict,
             const int* __restrict__ ws_sel, const float* __restrict__ ws_selp,
             float* __restrict__ out, float2* __restrict__ ws_lr)
{
    __shared__ float redL[4], redR[4];
    const int t = threadIdx.x;
    const int row = t >> 5, lr = t & 31;
    const size_t n = (size_t)blockIdx.x * 8 + row;

    int4 i0 = *(const int4*)(ws_sel + n * 8);
    int4 i1 = *(const int4*)(ws_sel + n * 8 + 4);
    const int idxs[8] = {i0.x, i0.y, i0.z, i0.w, i1.x, i1.y, i1.z, i1.w};
    float4 p0 = *(const float4*)(ws_selp + n * 8);
    float4 p1 = *(const float4*)(ws_selp + n * 8 + 4);
    const float p[8] = {p0.x, p0.y, p0.z, p0.w, p1.x, p1.y, p1.z, p1.w};

    // rep row: register-composed dense float4s, coalesced nt stores (8/thread)
    float* rr = out + 2 + (size_t)NELEM + (n << 10);
    #pragma unroll
    for (int q = 0; q < 8; ++q) {
        const int c0 = (q * 32 + lr) * 4;
        f32x4 v = {0.f, 0.f, 0.f, 0.f};
        #pragma unroll
        for (int j = 0; j < 8; ++j) {
            const int d = idxs[j] - c0;
            v[0] = (d == 0) ? p[j] : v[0];
            v[1] = (d == 1) ? p[j] : v[1];
            v[2] = (d == 2) ? p[j] : v[2];
            v[3] = (d == 3) ? p[j] : v[3];
        }
        __builtin_nontemporal_store(v, (f32x4*)(rr + c0));
    }

    // recon + fused MSE (flat .view semantics: raw-order x is correct here)
    float4 z4 = make_float4(0.f, 0.f, 0.f, 0.f);
    const float4* xp = (const float4*)(x + (n << 8)) + lr * 2;
    float4 xA = xp[0], xB = xp[1];
    float4 aA = z4, aB = z4;
    #pragma unroll
    for (int j = 0; j < 8; ++j) {
        const float4* dp = (const float4*)(dict + ((size_t)idxs[j] << 8)) + lr * 2;
        float4 dA = dp[0], dB = dp[1];
        aA.x += p[j] * dA.x; aA.y += p[j] * dA.y;
        aA.z += p[j] * dA.z; aA.w += p[j] * dA.w;
        aB.x += p[j] * dB.x; aB.y += p[j] * dB.y;
        aB.z += p[j] * dB.z; aB.w += p[j] * dB.w;
    }
    float* ro = out + 1 + (n << 8) + lr * 8;
    __builtin_nontemporal_store(__builtin_bit_cast(f32x4, aA), (f32x4*)ro);
    __builtin_nontemporal_store(__builtin_bit_cast(f32x4, aB), (f32x4*)(ro + 4));
    float e0 = xA.x - aA.x, e1 = xA.y - aA.y, e2 = xA.z - aA.z, e3 = xA.w - aA.w;
    float e4 = xB.x - aB.x, e5 = xB.y - aB.y, e6 = xB.z - aB.z, e7 = xB.w - aB.w;
    float lsum = ((e0*e0 + e1*e1) + (e2*e2 + e3*e3))
               + ((e4*e4 + e5*e5) + (e6*e6 + e7*e7));
    float rsum = 0.f;
    if (lr == 0) {
        #pragma unroll
        for (int j = 0; j < 8; ++j) rsum += p[j];
    }

    #pragma unroll
    for (int off = 32; off; off >>= 1) {
        lsum += __shfl_down(lsum, off);
        rsum += __shfl_down(rsum, off);
    }
    if ((t & 63) == 0) { redL[t >> 6] = lsum; redR[t >> 6] = rsum; }
    __syncthreads();
    if (t == 0) {
        ws_lr[blockIdx.x] = make_float2(
            (redL[0] + redL[1]) + (redL[2] + redL[3]),
            (redR[0] + redR[1]) + (redR[2] + redR[3]));
    }
}

// ---------------- finalize scalars ------------------------------------------
__global__ void dl_final(const float2* __restrict__ ws_lr,
                         const int* __restrict__ counts,
                         float* __restrict__ out)
{
    __shared__ float re[4], rl[4], rr[4];
    int t = threadIdx.x;
    float e = 0.f;
    for (int k = t; k < KDIM; k += 256) {
        float p = (float)counts[k] * (1.0f / 524288.0f);
        e += p * logf(p + 1e-10f);
    }
    float ls = 0.f, rs = 0.f;
    for (int i = t; i < 8192; i += 256) {
        float2 v = ws_lr[i];
        ls += v.x; rs += v.y;
    }
    #pragma unroll
    for (int off = 32; off; off >>= 1) {
        e += __shfl_down(e, off);
        ls += __shfl_down(ls, off);
        rs += __shfl_down(rs, off);
    }
    if ((t & 63) == 0) { re[t >> 6] = e; rl[t >> 6] = ls; rr[t >> 6] = rs; }
    __syncthreads();
    if (t == 0) {
        float et = (re[0] + re[1]) + (re[2] + re[3]);
        out[(size_t)NELEM + 1] = __expf(-et);                     // perplexity
        out[0] = 2.0f * ((rl[0] + rl[1]) + (rl[2] + rl[3])) / (float)NELEM
               + ((rr[0] + rr[1]) + (rr[2] + rr[3]));             // loss + reg
    }
}

extern "C" void kernel_launch(void* const* d_in, const int* in_sizes, int n_in,
                              void* d_out, int out_size, void* d_ws, size_t ws_size,
                              hipStream_t stream) {
    const float* x    = (const float*)d_in[0];
    const float* dict = (const float*)d_in[1];
    const float* Wm   = (const float*)d_in[2];
    const float* bv   = (const float*)d_in[3];
    float* out = (float*)d_out;

    int*    counts  = (int*)((char*)d_ws + WS_COUNTS);
    float*  dn      = (float*)((char*)d_ws + WS_DN);
    float*  b2      = (float*)((char*)d_ws + WS_B2);
    u16*    WhT     = (u16*)((char*)d_ws + WS_WH);
    u16*    DhT     = (u16*)((char*)d_ws + WS_DH);
    int*    ws_sel  = (int*)((char*)d_ws + WS_SEL);
    float*  ws_selp = (float*)((char*)d_ws + WS_SELP);
    float2* ws_lr   = (float2*)((char*)d_ws + WS_LR);

    hipMemsetAsync(d_ws, 0, 4608, stream);
    dl_prep<<<KDIM, 256, 0, stream>>>(Wm, dict, bv, WhT, DhT, dn, b2);
    dl_main<<<65536 / MROWS, 512, 0, stream>>>(x, Wm, bv, WhT, DhT, dn, b2,
                                               ws_sel, ws_selp);
    dl_count<<<64, 256, 0, stream>>>(ws_sel, counts);
    dl_tail<<<65536 / 8, 256, 0, stream>>>(x, dict, ws_sel, ws_selp, out, ws_lr);
    dl_final<<<1, 256, 0, stream>>>(ws_lr, counts, out);
}

// Round 17
// 326.752 us; speedup vs baseline: 1.0719x; 1.0719x over previous
//
#include <hip/hip_runtime.h>
#include <math.h>

#define CDIM 256
#define KDIM 1024
#define TOPK 8
#define MROWS 32
#define NELEM 16777216
#define L2E 1.4426950408889634f

typedef unsigned short u16;
typedef unsigned int u32;
typedef __attribute__((ext_vector_type(8))) short s16x8;
typedef __attribute__((ext_vector_type(8))) __bf16 b16x8;
typedef __attribute__((ext_vector_type(16))) float f32x16;
typedef __attribute__((ext_vector_type(4))) float f32x4;

#define ZERO16 {0.f,0.f,0.f,0.f,0.f,0.f,0.f,0.f,0.f,0.f,0.f,0.f,0.f,0.f,0.f,0.f}

// ws layout (bytes)
#define WS_COUNTS 64
#define WS_DN     4608
#define WS_B2     8704
#define WS_WH     16384                     // WhT: fragment-transposed, 512KB
#define WS_DH     (WS_WH + 524288)          // DhT: fragment-transposed, 512KB
#define WS_SEL    1064960                   // int[65536*8]   = 2 MB
#define WS_SELP   (WS_SEL + 2097152)        // float[65536*8] = 2 MB
#define WS_LR     (WS_SELP + 2097152)       // float2[8192]   = 64 KB

// K1 smem layout (bytes); overlays on xl/b2/dn after the main loop.
// xh/xl FRAGMENT-LINEAR: fragment f of row r at byte (f*32+r)*16, dims [8f,8f+8)
#define SM_XH   0        // 16K (LIVE through p-recompute)
#define SM_XL   16384    // 16K
#define SM_B2   32768    // 4K
#define SM_DN   36864    // 4K
#define SM_TOT  40960
#define SM_PD   16384    // 8K over xl
#define SM_PI   24576    // 8K over xl
#define SM_PM   32768    // 1K over b2
#define SM_PS   33792    // 1K over b2
#define SM_SELI 36864    // 1K over dn
#define SM_SELM 37888    // 128B over dn
#define SM_SELS 38016    // 128B over dn

__device__ __forceinline__ u16 f2bf(float f) {
    u32 u = __builtin_bit_cast(u32, f);
    u += 0x7FFFu + ((u >> 16) & 1u);
    return (u16)(u >> 16);
}
__device__ __forceinline__ float bf2f(u16 h) {
    return __builtin_bit_cast(float, ((u32)h) << 16);
}
__device__ __forceinline__ float hi2f(u32 u) {
    return __builtin_bit_cast(float, u & 0xFFFF0000u);
}
__device__ __forceinline__ f32x16 mfma16(s16x8 a, s16x8 b, f32x16 c) {
    return __builtin_amdgcn_mfma_f32_32x32x16_bf16(
        __builtin_bit_cast(b16x8, a), __builtin_bit_cast(b16x8, b), c, 0, 0, 0);
}
__device__ __forceinline__ u32 mono(float f) {
    u32 u = __builtin_bit_cast(u32, f);
    int m = (int)u >> 31;
    return u ^ (u32)(m | (int)0x80000000);
}
__device__ __forceinline__ float unmono(u32 v) {
    int m = (int)v >> 31;
    return __builtin_bit_cast(float, v ^ (u32)((int)0x80000000 | ~m));
}

// packed sorted-ascending insert: v_min_u32 + v_max_u32 per position
#define INSP(HK, PK) { u32 c_ = (PK); \
    _Pragma("unroll") \
    for (int p_ = 0; p_ < 8; ++p_) { \
        u32 lo_ = min(c_, HK[p_]); \
        u32 hi_ = max(c_, HK[p_]); \
        HK[p_] = lo_; c_ = hi_; } }

#define CE(HD, HX, A, B) { \
    bool sw_ = (HD[B] < HD[A]) || (HD[B] == HD[A] && HX[B] < HX[A]); \
    if (sw_) { float td_ = HD[A]; HD[A] = HD[B]; HD[B] = td_; \
               int ti_ = HX[A]; HX[A] = HX[B]; HX[B] = ti_; } }

#define MERGE8(HD, HX, OD, OI) { \
    _Pragma("unroll") \
    for (int j_ = 0; j_ < 8; ++j_) { \
        float bd_ = OD[7 - j_]; int bi_ = OI[7 - j_]; \
        if (bd_ < HD[j_] || (bd_ == HD[j_] && bi_ < HX[j_])) { \
            HD[j_] = bd_; HX[j_] = bi_; } } \
    CE(HD,HX,0,4) CE(HD,HX,1,5) CE(HD,HX,2,6) CE(HD,HX,3,7) \
    CE(HD,HX,0,2) CE(HD,HX,1,3) CE(HD,HX,4,6) CE(HD,HX,5,7) \
    CE(HD,HX,0,1) CE(HD,HX,2,3) CE(HD,HX,4,5) CE(HD,HX,6,7) }

#define SMAX_TILE(ACC, MM, SS) { \
    float lv_[16]; \
    _Pragma("unroll") \
    for (int rg_ = 0; rg_ < 4; ++rg_) { \
        lv_[4*rg_+0] = ACC[4*rg_+0] + bv4[rg_].x; \
        lv_[4*rg_+1] = ACC[4*rg_+1] + bv4[rg_].y; \
        lv_[4*rg_+2] = ACC[4*rg_+2] + bv4[rg_].z; \
        lv_[4*rg_+3] = ACC[4*rg_+3] + bv4[rg_].w; } \
    float x0_ = fmaxf(lv_[0],lv_[1]),  x1_ = fmaxf(lv_[2],lv_[3]); \
    float x2_ = fmaxf(lv_[4],lv_[5]),  x3_ = fmaxf(lv_[6],lv_[7]); \
    float x4_ = fmaxf(lv_[8],lv_[9]),  x5_ = fmaxf(lv_[10],lv_[11]); \
    float x6_ = fmaxf(lv_[12],lv_[13]), x7_ = fmaxf(lv_[14],lv_[15]); \
    x0_ = fmaxf(x0_,x1_); x2_ = fmaxf(x2_,x3_); \
    x4_ = fmaxf(x4_,x5_); x6_ = fmaxf(x6_,x7_); \
    float mn_ = fmaxf(fmaxf(fmaxf(x0_,x2_), fmaxf(x4_,x6_)), MM); \
    float e0_ = exp2f(lv_[0]-mn_) + exp2f(lv_[1]-mn_); \
    float e1_ = exp2f(lv_[2]-mn_) + exp2f(lv_[3]-mn_); \
    float e2_ = exp2f(lv_[4]-mn_) + exp2f(lv_[5]-mn_); \
    float e3_ = exp2f(lv_[6]-mn_) + exp2f(lv_[7]-mn_); \
    float e4_ = exp2f(lv_[8]-mn_) + exp2f(lv_[9]-mn_); \
    float e5_ = exp2f(lv_[10]-mn_) + exp2f(lv_[11]-mn_); \
    float e6_ = exp2f(lv_[12]-mn_) + exp2f(lv_[13]-mn_); \
    float e7_ = exp2f(lv_[14]-mn_) + exp2f(lv_[15]-mn_); \
    float sa_ = ((e0_+e1_) + (e2_+e3_)) + ((e4_+e5_) + (e6_+e7_)); \
    SS = SS * exp2f(MM - mn_) + sa_; MM = mn_; }

// ---------------- prepass: bf16 splits into FRAGMENT-TRANSPOSED layout ------
__global__ __launch_bounds__(256)
void dl_prep(const float* __restrict__ Wm, const float* __restrict__ dict,
             const float* __restrict__ bv,
             u16* __restrict__ WhT, u16* __restrict__ DhT,
             float* __restrict__ dn, float* __restrict__ b2)
{
    __shared__ float red[4];
    const int k = blockIdx.x, c = threadIdx.x;
    const size_t idx = ((size_t)k << 8) + c;
    const size_t dst = ((((size_t)(k >> 5) * 16 + (c >> 4)) * 64)
                        + (((c >> 3) & 1) << 5) + (k & 31)) * 8 + (c & 7);
    WhT[dst] = f2bf(Wm[idx] * L2E);
    float d = dict[idx];
    DhT[dst] = f2bf(-2.0f * d);
    float sq = d * d;
    #pragma unroll
    for (int off = 32; off; off >>= 1) sq += __shfl_down(sq, off);
    if ((c & 63) == 0) red[c >> 6] = sq;
    __syncthreads();
    if (c == 0) { dn[k] = red[0] + red[1] + red[2] + red[3]; b2[k] = bv[k] * L2E; }
}

// ---------------- K1: selection + probabilities (R15-exact, (512,6)) --------
__global__ __launch_bounds__(512, 6)
void dl_main(const float* __restrict__ x, const float* __restrict__ Wm,
             const float* __restrict__ bv, const u16* __restrict__ WhT,
             const u16* __restrict__ DhT, const float* __restrict__ dnp,
             const float* __restrict__ b2g,
             int* __restrict__ ws_sel, float* __restrict__ ws_selp)
{
    __shared__ __align__(16) char smem[SM_TOT];
    u16*   xh   = (u16*)(smem + SM_XH);
    u16*   xl   = (u16*)(smem + SM_XL);
    float* b2_s = (float*)(smem + SM_B2);
    float* dn_s = (float*)(smem + SM_DN);
    float* pd   = (float*)(smem + SM_PD);
    int*   pi   = (int*)(smem + SM_PI);
    float* pm   = (float*)(smem + SM_PM);
    float* ps   = (float*)(smem + SM_PS);
    int*   seli = (int*)(smem + SM_SELI);
    float* selm = (float*)(smem + SM_SELM);
    float* sels = (float*)(smem + SM_SELS);

    const int t = threadIdx.x;
    const int lane = t & 63;
    const int wid = t >> 6;
    const int n0 = blockIdx.x * MROWS;

    // ---- stage x -> bf16 hi/lo in FRAGMENT-LINEAR layout (write addr = t*16)
    {
        const int r = t & 31;
        const float* xb = x + ((size_t)(n0 >> 12) << 20) + (n0 & 4095) + r;
        #pragma unroll
        for (int gg = 0; gg < 2; ++gg) {
            const int f = (t >> 5) + gg * 16;     // fragment id, dims [8f,8f+8)
            const int c0 = f * 8;
            u32 hw[4], lw[4];
            #pragma unroll
            for (int i = 0; i < 8; i += 2) {
                float a0 = xb[(size_t)(c0 + i) << 12];
                float a1 = xb[(size_t)(c0 + i + 1) << 12];
                u16 h0 = f2bf(a0), h1 = f2bf(a1);
                u16 e0 = f2bf(a0 - bf2f(h0)), e1 = f2bf(a1 - bf2f(h1));
                hw[i >> 1] = (u32)h0 | ((u32)h1 << 16);
                lw[i >> 1] = (u32)e0 | ((u32)e1 << 16);
            }
            const int byte = (f * 32 + r) * 16;   // == (t + gg*512)*16, linear
            *(uint4*)((char*)xh + byte) = make_uint4(hw[0], hw[1], hw[2], hw[3]);
            *(uint4*)((char*)xl + byte) = make_uint4(lw[0], lw[1], lw[2], lw[3]);
        }
        b2_s[t] = b2g[t];  b2_s[512 + t] = b2g[512 + t];
        dn_s[t] = dnp[t];  dn_s[512 + t] = dnp[512 + t];
    }
    __syncthreads();

    const int arow = lane & 31, hl = lane >> 5;

    float m0 = -INFINITY, s0 = 0.f;
    u32 hk0[TOPK];
    #pragma unroll
    for (int j = 0; j < TOPK; ++j) hk0[j] = 0xFFFFFFFFu;

    // ---- barrier-free main loop: 4 chunks of 256 atoms
    #pragma unroll 1
    for (int ck = 0; ck < 4; ++ck) {
        const int ab = ck * 8 + wid;          // atom block: atoms [ab*32, +32)
        const u16* Wp = WhT + ((size_t)ab << 13) + (lane << 3);
        const u16* Dp = DhT + ((size_t)ab << 13) + (lane << 3);
        const int cb = (ck << 8) + (wid << 5) + (hl << 2);

        // L phase: logits from x_hi; atom load = contiguous 1KB per instr
        f32x16 accL = ZERO16;
        __builtin_amdgcn_s_setprio(1);
        #pragma unroll 8
        for (int kst = 0; kst < 16; ++kst) {
            int bo = kst * 1024 + lane * 16;
            s16x8 aw = *(const s16x8*)(Wp + kst * 512);
            s16x8 bh = *(const s16x8*)((const char*)xh + bo);
            accL = mfma16(aw, bh, accL);
        }
        __builtin_amdgcn_s_setprio(0);

        float4 bv4[4];
        #pragma unroll
        for (int rg = 0; rg < 4; ++rg)
            bv4[rg] = *(const float4*)(b2_s + cb + rg * 8);
        SMAX_TILE(accL, m0, s0)

        // D phase: -2 x.d_hi with full-x (hi+lo) precision
        f32x16 accD = ZERO16;
        __builtin_amdgcn_s_setprio(1);
        #pragma unroll 8
        for (int kst = 0; kst < 16; ++kst) {
            int bo = kst * 1024 + lane * 16;
            s16x8 adh = *(const s16x8*)(Dp + kst * 512);
            s16x8 bh = *(const s16x8*)((const char*)xh + bo);
            s16x8 bl = *(const s16x8*)((const char*)xl + bo);
            accD = mfma16(adh, bh, accD);
            accD = mfma16(adh, bl, accD);
        }
        __builtin_amdgcn_s_setprio(0);

        float4 n44[4];
        #pragma unroll
        for (int rg = 0; rg < 4; ++rg)
            n44[rg] = *(const float4*)(dn_s + cb + rg * 8);
        const u32 ob = (u32)(ck << 4);
        #pragma unroll
        for (int rg = 0; rg < 4; ++rg) {
            u32 o0 = ob + rg * 4;
            float d0 = n44[rg].x + accD[4*rg+0];
            float d1 = n44[rg].y + accD[4*rg+1];
            float d2 = n44[rg].z + accD[4*rg+2];
            float d3 = n44[rg].w + accD[4*rg+3];
            INSP(hk0, (mono(d0) & ~63u) | (o0 + 0))
            INSP(hk0, (mono(d1) & ~63u) | (o0 + 1))
            INSP(hk0, (mono(d2) & ~63u) | (o0 + 2))
            INSP(hk0, (mono(d3) & ~63u) | (o0 + 3))
        }
    }

    // ---- decode packed keys -> (dist, global atom idx)
    float hd0[TOPK];
    int hix0[TOPK];
    #pragma unroll
    for (int j = 0; j < TOPK; ++j) {
        u32 v = hk0[j]; int o = (int)(v & 63u);
        hd0[j] = unmono(v & ~63u);
        hix0[j] = ((o >> 4) << 8) + (wid << 5) + (((o >> 2) & 3) << 3) + (hl << 2) + (o & 3);
    }

    // ---- intra-wave merge (lane n <-> n+32)
    {
        float mo = __shfl_xor(m0, 32), so = __shfl_xor(s0, 32);
        float mn = fmaxf(m0, mo);
        s0 = s0 * exp2f(m0 - mn) + so * exp2f(mo - mn);
        m0 = mn;
        float od[TOPK]; int oi[TOPK];
        #pragma unroll
        for (int j = 0; j < TOPK; ++j) {
            od[j] = __shfl_xor(hd0[j], 32); oi[j] = __shfl_xor(hix0[j], 32);
        }
        MERGE8(hd0, hix0, od, oi)
    }

    // ---- publish the 8 wave-lists per row (overlay on dead xl/b2)
    __syncthreads();
    if (lane < 32) {
        const int base = arow * 64 + wid * 8;
        #pragma unroll
        for (int j = 0; j < TOPK; ++j) { pd[base + j] = hd0[j]; pi[base + j] = hix0[j]; }
        pm[arow * 8 + wid] = m0; ps[arow * 8 + wid] = s0;
    }
    __syncthreads();

    // ---- final merge (8 threads/row) -> seli/selm/sels (LDS) + ws_sel
    if (t < 256) {
        const int row = t >> 3, src = t & 7;
        float hd[TOPK]; int hix[TOPK];
        #pragma unroll
        for (int j = 0; j < TOPK; ++j) {
            hd[j] = pd[row * 64 + src * 8 + j];
            hix[j] = pi[row * 64 + src * 8 + j];
        }
        float m = pm[row * 8 + src], s = ps[row * 8 + src];
        #pragma unroll
        for (int k = 1; k <= 4; k <<= 1) {
            float mo = __shfl_xor(m, k), so = __shfl_xor(s, k);
            float mn = fmaxf(m, mo);
            s = s * exp2f(m - mn) + so * exp2f(mo - mn);
            m = mn;
            float od[TOPK]; int oi[TOPK];
            #pragma unroll
            for (int j = 0; j < TOPK; ++j) {
                od[j] = __shfl_xor(hd[j], k); oi[j] = __shfl_xor(hix[j], k);
            }
            MERGE8(hd, hix, od, oi)
        }
        if (src == 0) {
            size_t n = (size_t)(n0 + row);
            selm[row] = m;
            sels[row] = 1.0f / s;
            #pragma unroll
            for (int j = 0; j < TOPK; ++j) seli[row * 8 + j] = hix[j];
            *(int4*)(ws_sel + n * 8)     = make_int4(hix[0], hix[1], hix[2], hix[3]);
            *(int4*)(ws_sel + n * 8 + 4) = make_int4(hix[4], hix[5], hix[6], hix[7]);
        }
    }
    __syncthreads();

    // ---- recompute winner logits from LDS xh (true x_flat rows) + fp32 W, b
    {
        const int row = t >> 4, j = (t >> 1) & 7, half = t & 1;
        const int idxw = seli[row * 8 + j];
        const float4* wp = (const float4*)(Wm + ((size_t)idxw << 8)) + half * 32;
        float ax = 0.f, ay = 0.f, az = 0.f, aw2 = 0.f;
        #pragma unroll 8
        for (int i = 0; i < 16; ++i) {
            const int byte = ((half * 16 + i) * 32 + row) * 16;  // fragment-linear
            uint4 H = *(const uint4*)((const char*)xh + byte);
            float4 w0 = wp[i * 2], w1 = wp[i * 2 + 1];
            ax += bf2f((u16)H.x) * w0.x; ay += hi2f(H.x) * w0.y;
            az += bf2f((u16)H.y) * w0.z; aw2 += hi2f(H.y) * w0.w;
            ax += bf2f((u16)H.z) * w1.x; ay += hi2f(H.z) * w1.y;
            az += bf2f((u16)H.w) * w1.z; aw2 += hi2f(H.w) * w1.w;
        }
        float a = (ax + ay) + (az + aw2);
        a += __shfl_xor(a, 1);
        if (half == 0) {
            float p = exp2f((a + bv[idxw]) * L2E - selm[row]) * sels[row];
            ws_selp[(size_t)(n0 + row) * 8 + j] = p;
        }
    }
}

// ---------------- K2c: counts via LDS histogram (skew-proof) ----------------
__global__ __launch_bounds__(256)
void dl_count(const int* __restrict__ ws_sel, int* __restrict__ counts)
{
    __shared__ int hist[KDIM];
    const int t = threadIdx.x;
    #pragma unroll
    for (int i = 0; i < 4; ++i) hist[t + i * 256] = 0;
    __syncthreads();
    const int4* src = (const int4*)(ws_sel + (size_t)blockIdx.x * 8192);
    #pragma unroll
    for (int i = 0; i < 8; ++i) {
        int4 v = src[(size_t)i * 256 + t];
        atomicAdd(&hist[v.x], 1); atomicAdd(&hist[v.y], 1);
        atomicAdd(&hist[v.z], 1); atomicAdd(&hist[v.w], 1);
    }
    __syncthreads();
    #pragma unroll
    for (int i = 0; i < 4; ++i) {
        int k = t + i * 256;
        int c = hist[k];
        if (c) atomicAdd(&counts[k], c);
    }
}

// ---------------- K2: merged tail — rep compose + recon + MSE + partials ----
__global__ __launch_bounds__(256, 8)
void dl_tail(const float* __restrict__ x, const float* __restrict__ dict,
             const int* __restrict__ ws_sel, const float* __restrict__ ws_selp,
             float* __restrict__ out, float2* __restrict__ ws_lr)
{
    __shared__ float redL[4], redR[4];
    const int t = threadIdx.x;
    const int row = t >> 5, lr = t & 31;
    const size_t n = (size_t)blockIdx.x * 8 + row;

    int4 i0 = *(const int4*)(ws_sel + n * 8);
    int4 i1 = *(const int4*)(ws_sel + n * 8 + 4);
    const int idxs[8] = {i0.x, i0.y, i0.z, i0.w, i1.x, i1.y, i1.z, i1.w};
    float4 p0 = *(const float4*)(ws_selp + n * 8);
    float4 p1 = *(const float4*)(ws_selp + n * 8 + 4);
    const float p[8] = {p0.x, p0.y, p0.z, p0.w, p1.x, p1.y, p1.z, p1.w};

    // rep row: register-composed dense float4s, coalesced nt stores (8/thread)
    float* rr = out + 2 + (size_t)NELEM + (n << 10);
    #pragma unroll
    for (int q = 0; q < 8; ++q) {
        const int c0 = (q * 32 + lr) * 4;
        f32x4 v = {0.f, 0.f, 0.f, 0.f};
        #pragma unroll
        for (int j = 0; j < 8; ++j) {
            const int d = idxs[j] - c0;
            v[0] = (d == 0) ? p[j] : v[0];
            v[1] = (d == 1) ? p[j] : v[1];
            v[2] = (d == 2) ? p[j] : v[2];
            v[3] = (d == 3) ? p[j] : v[3];
        }
        __builtin_nontemporal_store(v, (f32x4*)(rr + c0));
    }

    // recon + fused MSE (flat .view semantics: raw-order x is correct here)
    float4 z4 = make_float4(0.f, 0.f, 0.f, 0.f);
    const float4* xp = (const float4*)(x + (n << 8)) + lr * 2;
    float4 xA = xp[0], xB = xp[1];
    float4 aA = z4, aB = z4;
    #pragma unroll
    for (int j = 0; j < 8; ++j) {
        const float4* dp = (const float4*)(dict + ((size_t)idxs[j] << 8)) + lr * 2;
        float4 dA = dp[0], dB = dp[1];
        aA.x += p[j] * dA.x; aA.y += p[j] * dA.y;
        aA.z += p[j] * dA.z; aA.w += p[j] * dA.w;
        aB.x += p[j] * dB.x; aB.y += p[j] * dB.y;
        aB.z += p[j] * dB.z; aB.w += p[j] * dB.w;
    }
    float* ro = out + 1 + (n << 8) + lr * 8;
    __builtin_nontemporal_store(__builtin_bit_cast(f32x4, aA), (f32x4*)ro);
    __builtin_nontemporal_store(__builtin_bit_cast(f32x4, aB), (f32x4*)(ro + 4));
    float e0 = xA.x - aA.x, e1 = xA.y - aA.y, e2 = xA.z - aA.z, e3 = xA.w - aA.w;
    float e4 = xB.x - aB.x, e5 = xB.y - aB.y, e6 = xB.z - aB.z, e7 = xB.w - aB.w;
    float lsum = ((e0*e0 + e1*e1) + (e2*e2 + e3*e3))
               + ((e4*e4 + e5*e5) + (e6*e6 + e7*e7));
    float rsum = 0.f;
    if (lr == 0) {
        #pragma unroll
        for (int j = 0; j < 8; ++j) rsum += p[j];
    }

    #pragma unroll
    for (int off = 32; off; off >>= 1) {
        lsum += __shfl_down(lsum, off);
        rsum += __shfl_down(rsum, off);
    }
    if ((t & 63) == 0) { redL[t >> 6] = lsum; redR[t >> 6] = rsum; }
    __syncthreads();
    if (t == 0) {
        ws_lr[blockIdx.x] = make_float2(
            (redL[0] + redL[1]) + (redL[2] + redL[3]),
            (redR[0] + redR[1]) + (redR[2] + redR[3]));
    }
}

// ---------------- finalize scalars ------------------------------------------
__global__ void dl_final(const float2* __restrict__ ws_lr,
                         const int* __restrict__ counts,
                         float* __restrict__ out)
{
    __shared__ float re[4], rl[4], rr[4];
    int t = threadIdx.x;
    float e = 0.f;
    for (int k = t; k < KDIM; k += 256) {
        float p = (float)counts[k] * (1.0f / 524288.0f);
        e += p * logf(p + 1e-10f);
    }
    float ls = 0.f, rs = 0.f;
    for (int i = t; i < 8192; i += 256) {
        float2 v = ws_lr[i];
        ls += v.x; rs += v.y;
    }
    #pragma unroll
    for (int off = 32; off; off >>= 1) {
        e += __shfl_down(e, off);
        ls += __shfl_down(ls, off);
        rs += __shfl_down(rs, off);
    }
    if ((t & 63) == 0) { re[t >> 6] = e; rl[t >> 6] = ls; rr[t >> 6] = rs; }
    __syncthreads();
    if (t == 0) {
        float et = (re[0] + re[1]) + (re[2] + re[3]);
        out[(size_t)NELEM + 1] = __expf(-et);                     // perplexity
        out[0] = 2.0f * ((rl[0] + rl[1]) + (rl[2] + rl[3])) / (float)NELEM
               + ((rr[0] + rr[1]) + (rr[2] + rr[3]));             // loss + reg
    }
}

extern "C" void kernel_launch(void* const* d_in, const int* in_sizes, int n_in,
                              void* d_out, int out_size, void* d_ws, size_t ws_size,
                              hipStream_t stream) {
    const float* x    = (const float*)d_in[0];
    const float* dict = (const float*)d_in[1];
    const float* Wm   = (const float*)d_in[2];
    const float* bv   = (const float*)d_in[3];
    float* out = (float*)d_out;

    int*    counts  = (int*)((char*)d_ws + WS_COUNTS);
    float*  dn      = (float*)((char*)d_ws + WS_DN);
    float*  b2      = (float*)((char*)d_ws + WS_B2);
    u16*    WhT     = (u16*)((char*)d_ws + WS_WH);
    u16*    DhT     = (u16*)((char*)d_ws + WS_DH);
    int*    ws_sel  = (int*)((char*)d_ws + WS_SEL);
    float*  ws_selp = (float*)((char*)d_ws + WS_SELP);
    float2* ws_lr   = (float2*)((char*)d_ws + WS_LR);

    hipMemsetAsync(d_ws, 0, 4608, stream);
    dl_prep<<<KDIM, 256, 0, stream>>>(Wm, dict, bv, WhT, DhT, dn, b2);
    dl_main<<<65536 / MROWS, 512, 0, stream>>>(x, Wm, bv, WhT, DhT, dn, b2,
                                               ws_sel, ws_selp);
    dl_count<<<64, 256, 0, stream>>>(ws_sel, counts);
    dl_tail<<<65536 / 8, 256, 0, stream>>>(x, dict, ws_sel, ws_selp, out, ws_lr);
    dl_final<<<1, 256, 0, stream>>>(ws_lr, counts, out);
}

// Round 18
// 322.522 us; speedup vs baseline: 1.0859x; 1.0131x over previous
//
#include <hip/hip_runtime.h>
#include <math.h>

#define CDIM 256
#define KDIM 1024
#define TOPK 8
#define MROWS 32
#define NELEM 16777216
#define L2E 1.4426950408889634f

typedef unsigned short u16;
typedef unsigned int u32;
typedef __attribute__((ext_vector_type(8))) short s16x8;
typedef __attribute__((ext_vector_type(8))) __bf16 b16x8;
typedef __attribute__((ext_vector_type(16))) float f32x16;
typedef __attribute__((ext_vector_type(4))) float f32x4;

#define ZERO16 {0.f,0.f,0.f,0.f,0.f,0.f,0.f,0.f,0.f,0.f,0.f,0.f,0.f,0.f,0.f,0.f}

// ws layout (bytes)
#define WS_COUNTS 64
#define WS_DN     4608
#define WS_B2     8704
#define WS_WH     16384                     // WhT: fragment-transposed, 512KB
#define WS_DH     (WS_WH + 524288)          // DhT: fragment-transposed, 512KB
#define WS_SEL    1064960                   // int[65536*8]   = 2 MB
#define WS_SELP   (WS_SEL + 2097152)        // float[65536*8] = 2 MB
#define WS_LR     (WS_SELP + 2097152)       // float2[8192]   = 64 KB

// K1 smem layout (bytes); overlays on xl/b2/dn after the main loop.
// xh/xl FRAGMENT-LINEAR: fragment f of row r at byte (f*32+r)*16, dims [8f,8f+8)
#define SM_XH   0        // 16K (LIVE through p-recompute)
#define SM_XL   16384    // 16K
#define SM_B2   32768    // 4K
#define SM_DN   36864    // 4K
#define SM_TOT  40960
#define SM_PD   16384    // 8K over xl
#define SM_PI   24576    // 8K over xl
#define SM_PM   32768    // 1K over b2
#define SM_PS   33792    // 1K over b2
#define SM_SELI 36864    // 1K over dn
#define SM_SELM 37888    // 128B over dn
#define SM_SELS 38016    // 128B over dn

__device__ __forceinline__ u16 f2bf(float f) {
    u32 u = __builtin_bit_cast(u32, f);
    u += 0x7FFFu + ((u >> 16) & 1u);
    return (u16)(u >> 16);
}
__device__ __forceinline__ float bf2f(u16 h) {
    return __builtin_bit_cast(float, ((u32)h) << 16);
}
__device__ __forceinline__ float hi2f(u32 u) {
    return __builtin_bit_cast(float, u & 0xFFFF0000u);
}
__device__ __forceinline__ f32x16 mfma16(s16x8 a, s16x8 b, f32x16 c) {
    return __builtin_amdgcn_mfma_f32_32x32x16_bf16(
        __builtin_bit_cast(b16x8, a), __builtin_bit_cast(b16x8, b), c, 0, 0, 0);
}
__device__ __forceinline__ u32 mono(float f) {
    u32 u = __builtin_bit_cast(u32, f);
    int m = (int)u >> 31;
    return u ^ (u32)(m | (int)0x80000000);
}
__device__ __forceinline__ float unmono(u32 v) {
    int m = (int)v >> 31;
    return __builtin_bit_cast(float, v ^ (u32)((int)0x80000000 | ~m));
}

// compare-exchange on packed u32 keys: v_min_u32 + v_max_u32
#define CEK(K, A, B) { u32 lo_ = min(K[A], K[B]); u32 hi_ = max(K[A], K[B]); \
                       K[A] = lo_; K[B] = hi_; }

// 4-wide batch insert: sort c[0..3], then bitonic-merge into sorted hk[0..7]
// (selection = min against reversed INF-padded list, then 3-layer cleanup).
// Produces EXACTLY the same top-8 set as 4 sequential sorted inserts.
#define MERGE4(HK, C) { \
    CEK(C,0,1) CEK(C,2,3) CEK(C,0,2) CEK(C,1,3) CEK(C,1,2) \
    HK[4] = min(HK[4], C[3]); HK[5] = min(HK[5], C[2]); \
    HK[6] = min(HK[6], C[1]); HK[7] = min(HK[7], C[0]); \
    CEK(HK,0,4) CEK(HK,1,5) CEK(HK,2,6) CEK(HK,3,7) \
    CEK(HK,0,2) CEK(HK,1,3) CEK(HK,4,6) CEK(HK,5,7) \
    CEK(HK,0,1) CEK(HK,2,3) CEK(HK,4,5) CEK(HK,6,7) }

#define CE(HD, HX, A, B) { \
    bool sw_ = (HD[B] < HD[A]) || (HD[B] == HD[A] && HX[B] < HX[A]); \
    if (sw_) { float td_ = HD[A]; HD[A] = HD[B]; HD[B] = td_; \
               int ti_ = HX[A]; HX[A] = HX[B]; HX[B] = ti_; } }

#define MERGE8(HD, HX, OD, OI) { \
    _Pragma("unroll") \
    for (int j_ = 0; j_ < 8; ++j_) { \
        float bd_ = OD[7 - j_]; int bi_ = OI[7 - j_]; \
        if (bd_ < HD[j_] || (bd_ == HD[j_] && bi_ < HX[j_])) { \
            HD[j_] = bd_; HX[j_] = bi_; } } \
    CE(HD,HX,0,4) CE(HD,HX,1,5) CE(HD,HX,2,6) CE(HD,HX,3,7) \
    CE(HD,HX,0,2) CE(HD,HX,1,3) CE(HD,HX,4,6) CE(HD,HX,5,7) \
    CE(HD,HX,0,1) CE(HD,HX,2,3) CE(HD,HX,4,5) CE(HD,HX,6,7) }

#define SMAX_TILE(ACC, MM, SS) { \
    float lv_[16]; \
    _Pragma("unroll") \
    for (int rg_ = 0; rg_ < 4; ++rg_) { \
        lv_[4*rg_+0] = ACC[4*rg_+0] + bv4[rg_].x; \
        lv_[4*rg_+1] = ACC[4*rg_+1] + bv4[rg_].y; \
        lv_[4*rg_+2] = ACC[4*rg_+2] + bv4[rg_].z; \
        lv_[4*rg_+3] = ACC[4*rg_+3] + bv4[rg_].w; } \
    float x0_ = fmaxf(lv_[0],lv_[1]),  x1_ = fmaxf(lv_[2],lv_[3]); \
    float x2_ = fmaxf(lv_[4],lv_[5]),  x3_ = fmaxf(lv_[6],lv_[7]); \
    float x4_ = fmaxf(lv_[8],lv_[9]),  x5_ = fmaxf(lv_[10],lv_[11]); \
    float x6_ = fmaxf(lv_[12],lv_[13]), x7_ = fmaxf(lv_[14],lv_[15]); \
    x0_ = fmaxf(x0_,x1_); x2_ = fmaxf(x2_,x3_); \
    x4_ = fmaxf(x4_,x5_); x6_ = fmaxf(x6_,x7_); \
    float mn_ = fmaxf(fmaxf(fmaxf(x0_,x2_), fmaxf(x4_,x6_)), MM); \
    float e0_ = exp2f(lv_[0]-mn_) + exp2f(lv_[1]-mn_); \
    float e1_ = exp2f(lv_[2]-mn_) + exp2f(lv_[3]-mn_); \
    float e2_ = exp2f(lv_[4]-mn_) + exp2f(lv_[5]-mn_); \
    float e3_ = exp2f(lv_[6]-mn_) + exp2f(lv_[7]-mn_); \
    float e4_ = exp2f(lv_[8]-mn_) + exp2f(lv_[9]-mn_); \
    float e5_ = exp2f(lv_[10]-mn_) + exp2f(lv_[11]-mn_); \
    float e6_ = exp2f(lv_[12]-mn_) + exp2f(lv_[13]-mn_); \
    float e7_ = exp2f(lv_[14]-mn_) + exp2f(lv_[15]-mn_); \
    float sa_ = ((e0_+e1_) + (e2_+e3_)) + ((e4_+e5_) + (e6_+e7_)); \
    SS = SS * exp2f(MM - mn_) + sa_; MM = mn_; }

// ---------------- prepass: bf16 splits into FRAGMENT-TRANSPOSED layout ------
__global__ __launch_bounds__(256)
void dl_prep(const float* __restrict__ Wm, const float* __restrict__ dict,
             const float* __restrict__ bv,
             u16* __restrict__ WhT, u16* __restrict__ DhT,
             float* __restrict__ dn, float* __restrict__ b2)
{
    __shared__ float red[4];
    const int k = blockIdx.x, c = threadIdx.x;
    const size_t idx = ((size_t)k << 8) + c;
    const size_t dst = ((((size_t)(k >> 5) * 16 + (c >> 4)) * 64)
                        + (((c >> 3) & 1) << 5) + (k & 31)) * 8 + (c & 7);
    WhT[dst] = f2bf(Wm[idx] * L2E);
    float d = dict[idx];
    DhT[dst] = f2bf(-2.0f * d);
    float sq = d * d;
    #pragma unroll
    for (int off = 32; off; off >>= 1) sq += __shfl_down(sq, off);
    if ((c & 63) == 0) red[c >> 6] = sq;
    __syncthreads();
    if (c == 0) { dn[k] = red[0] + red[1] + red[2] + red[3]; b2[k] = bv[k] * L2E; }
}

// ---------------- K1: selection + probabilities (R17 + 4-wide insert) -------
__global__ __launch_bounds__(512, 6)
void dl_main(const float* __restrict__ x, const float* __restrict__ Wm,
             const float* __restrict__ bv, const u16* __restrict__ WhT,
             const u16* __restrict__ DhT, const float* __restrict__ dnp,
             const float* __restrict__ b2g,
             int* __restrict__ ws_sel, float* __restrict__ ws_selp)
{
    __shared__ __align__(16) char smem[SM_TOT];
    u16*   xh   = (u16*)(smem + SM_XH);
    u16*   xl   = (u16*)(smem + SM_XL);
    float* b2_s = (float*)(smem + SM_B2);
    float* dn_s = (float*)(smem + SM_DN);
    float* pd   = (float*)(smem + SM_PD);
    int*   pi   = (int*)(smem + SM_PI);
    float* pm   = (float*)(smem + SM_PM);
    float* ps   = (float*)(smem + SM_PS);
    int*   seli = (int*)(smem + SM_SELI);
    float* selm = (float*)(smem + SM_SELM);
    float* sels = (float*)(smem + SM_SELS);

    const int t = threadIdx.x;
    const int lane = t & 63;
    const int wid = t >> 6;
    const int n0 = blockIdx.x * MROWS;

    // ---- stage x -> bf16 hi/lo in FRAGMENT-LINEAR layout (write addr = t*16)
    {
        const int r = t & 31;
        const float* xb = x + ((size_t)(n0 >> 12) << 20) + (n0 & 4095) + r;
        #pragma unroll
        for (int gg = 0; gg < 2; ++gg) {
            const int f = (t >> 5) + gg * 16;     // fragment id, dims [8f,8f+8)
            const int c0 = f * 8;
            u32 hw[4], lw[4];
            #pragma unroll
            for (int i = 0; i < 8; i += 2) {
                float a0 = xb[(size_t)(c0 + i) << 12];
                float a1 = xb[(size_t)(c0 + i + 1) << 12];
                u16 h0 = f2bf(a0), h1 = f2bf(a1);
                u16 e0 = f2bf(a0 - bf2f(h0)), e1 = f2bf(a1 - bf2f(h1));
                hw[i >> 1] = (u32)h0 | ((u32)h1 << 16);
                lw[i >> 1] = (u32)e0 | ((u32)e1 << 16);
            }
            const int byte = (f * 32 + r) * 16;   // == (t + gg*512)*16, linear
            *(uint4*)((char*)xh + byte) = make_uint4(hw[0], hw[1], hw[2], hw[3]);
            *(uint4*)((char*)xl + byte) = make_uint4(lw[0], lw[1], lw[2], lw[3]);
        }
        b2_s[t] = b2g[t];  b2_s[512 + t] = b2g[512 + t];
        dn_s[t] = dnp[t];  dn_s[512 + t] = dnp[512 + t];
    }
    __syncthreads();

    const int arow = lane & 31, hl = lane >> 5;

    float m0 = -INFINITY, s0 = 0.f;
    u32 hk0[TOPK];
    #pragma unroll
    for (int j = 0; j < TOPK; ++j) hk0[j] = 0xFFFFFFFFu;

    // ---- barrier-free main loop: 4 chunks of 256 atoms
    #pragma unroll 1
    for (int ck = 0; ck < 4; ++ck) {
        const int ab = ck * 8 + wid;          // atom block: atoms [ab*32, +32)
        const u16* Wp = WhT + ((size_t)ab << 13) + (lane << 3);
        const u16* Dp = DhT + ((size_t)ab << 13) + (lane << 3);
        const int cb = (ck << 8) + (wid << 5) + (hl << 2);

        // L phase: logits from x_hi; atom load = contiguous 1KB per instr
        f32x16 accL = ZERO16;
        __builtin_amdgcn_s_setprio(1);
        #pragma unroll 8
        for (int kst = 0; kst < 16; ++kst) {
            int bo = kst * 1024 + lane * 16;
            s16x8 aw = *(const s16x8*)(Wp + kst * 512);
            s16x8 bh = *(const s16x8*)((const char*)xh + bo);
            accL = mfma16(aw, bh, accL);
        }
        __builtin_amdgcn_s_setprio(0);

        float4 bv4[4];
        #pragma unroll
        for (int rg = 0; rg < 4; ++rg)
            bv4[rg] = *(const float4*)(b2_s + cb + rg * 8);
        SMAX_TILE(accL, m0, s0)

        // D phase: -2 x.d_hi with full-x (hi+lo) precision
        f32x16 accD = ZERO16;
        __builtin_amdgcn_s_setprio(1);
        #pragma unroll 8
        for (int kst = 0; kst < 16; ++kst) {
            int bo = kst * 1024 + lane * 16;
            s16x8 adh = *(const s16x8*)(Dp + kst * 512);
            s16x8 bh = *(const s16x8*)((const char*)xh + bo);
            s16x8 bl = *(const s16x8*)((const char*)xl + bo);
            accD = mfma16(adh, bh, accD);
            accD = mfma16(adh, bl, accD);
        }
        __builtin_amdgcn_s_setprio(0);

        float4 n44[4];
        #pragma unroll
        for (int rg = 0; rg < 4; ++rg)
            n44[rg] = *(const float4*)(dn_s + cb + rg * 8);
        const u32 ob = (u32)(ck << 4);
        #pragma unroll
        for (int rg = 0; rg < 4; ++rg) {
            const u32 o0 = ob + rg * 4;
            u32 c[4];
            c[0] = (mono(n44[rg].x + accD[4*rg+0]) & ~63u) | (o0 + 0);
            c[1] = (mono(n44[rg].y + accD[4*rg+1]) & ~63u) | (o0 + 1);
            c[2] = (mono(n44[rg].z + accD[4*rg+2]) & ~63u) | (o0 + 2);
            c[3] = (mono(n44[rg].w + accD[4*rg+3]) & ~63u) | (o0 + 3);
            MERGE4(hk0, c)
        }
    }

    // ---- decode packed keys -> (dist, global atom idx)
    float hd0[TOPK];
    int hix0[TOPK];
    #pragma unroll
    for (int j = 0; j < TOPK; ++j) {
        u32 v = hk0[j]; int o = (int)(v & 63u);
        hd0[j] = unmono(v & ~63u);
        hix0[j] = ((o >> 4) << 8) + (wid << 5) + (((o >> 2) & 3) << 3) + (hl << 2) + (o & 3);
    }

    // ---- intra-wave merge (lane n <-> n+32)
    {
        float mo = __shfl_xor(m0, 32), so = __shfl_xor(s0, 32);
        float mn = fmaxf(m0, mo);
        s0 = s0 * exp2f(m0 - mn) + so * exp2f(mo - mn);
        m0 = mn;
        float od[TOPK]; int oi[TOPK];
        #pragma unroll
        for (int j = 0; j < TOPK; ++j) {
            od[j] = __shfl_xor(hd0[j], 32); oi[j] = __shfl_xor(hix0[j], 32);
        }
        MERGE8(hd0, hix0, od, oi)
    }

    // ---- publish the 8 wave-lists per row (overlay on dead xl/b2)
    __syncthreads();
    if (lane < 32) {
        const int base = arow * 64 + wid * 8;
        #pragma unroll
        for (int j = 0; j < TOPK; ++j) { pd[base + j] = hd0[j]; pi[base + j] = hix0[j]; }
        pm[arow * 8 + wid] = m0; ps[arow * 8 + wid] = s0;
    }
    __syncthreads();

    // ---- final merge (8 threads/row) -> seli/selm/sels (LDS) + ws_sel
    if (t < 256) {
        const int row = t >> 3, src = t & 7;
        float hd[TOPK]; int hix[TOPK];
        #pragma unroll
        for (int j = 0; j < TOPK; ++j) {
            hd[j] = pd[row * 64 + src * 8 + j];
            hix[j] = pi[row * 64 + src * 8 + j];
        }
        float m = pm[row * 8 + src], s = ps[row * 8 + src];
        #pragma unroll
        for (int k = 1; k <= 4; k <<= 1) {
            float mo = __shfl_xor(m, k), so = __shfl_xor(s, k);
            float mn = fmaxf(m, mo);
            s = s * exp2f(m - mn) + so * exp2f(mo - mn);
            m = mn;
            float od[TOPK]; int oi[TOPK];
            #pragma unroll
            for (int j = 0; j < TOPK; ++j) {
                od[j] = __shfl_xor(hd[j], k); oi[j] = __shfl_xor(hix[j], k);
            }
            MERGE8(hd, hix, od, oi)
        }
        if (src == 0) {
            size_t n = (size_t)(n0 + row);
            selm[row] = m;
            sels[row] = 1.0f / s;
            #pragma unroll
            for (int j = 0; j < TOPK; ++j) seli[row * 8 + j] = hix[j];
            *(int4*)(ws_sel + n * 8)     = make_int4(hix[0], hix[1], hix[2], hix[3]);
            *(int4*)(ws_sel + n * 8 + 4) = make_int4(hix[4], hix[5], hix[6], hix[7]);
        }
    }
    __syncthreads();

    // ---- recompute winner logits from LDS xh (true x_flat rows) + fp32 W, b
    {
        const int row = t >> 4, j = (t >> 1) & 7, half = t & 1;
        const int idxw = seli[row * 8 + j];
        const float4* wp = (const float4*)(Wm + ((size_t)idxw << 8)) + half * 32;
        float ax = 0.f, ay = 0.f, az = 0.f, aw2 = 0.f;
        #pragma unroll 8
        for (int i = 0; i < 16; ++i) {
            const int byte = ((half * 16 + i) * 32 + row) * 16;  // fragment-linear
            uint4 H = *(const uint4*)((const char*)xh + byte);
            float4 w0 = wp[i * 2], w1 = wp[i * 2 + 1];
            ax += bf2f((u16)H.x) * w0.x; ay += hi2f(H.x) * w0.y;
            az += bf2f((u16)H.y) * w0.z; aw2 += hi2f(H.y) * w0.w;
            ax += bf2f((u16)H.z) * w1.x; ay += hi2f(H.z) * w1.y;
            az += bf2f((u16)H.w) * w1.z; aw2 += hi2f(H.w) * w1.w;
        }
        float a = (ax + ay) + (az + aw2);
        a += __shfl_xor(a, 1);
        if (half == 0) {
            float p = exp2f((a + bv[idxw]) * L2E - selm[row]) * sels[row];
            ws_selp[(size_t)(n0 + row) * 8 + j] = p;
        }
    }
}

// ---------------- K2c: counts via LDS histogram (skew-proof) ----------------
__global__ __launch_bounds__(256)
void dl_count(const int* __restrict__ ws_sel, int* __restrict__ counts)
{
    __shared__ int hist[KDIM];
    const int t = threadIdx.x;
    #pragma unroll
    for (int i = 0; i < 4; ++i) hist[t + i * 256] = 0;
    __syncthreads();
    const int4* src = (const int4*)(ws_sel + (size_t)blockIdx.x * 8192);
    #pragma unroll
    for (int i = 0; i < 8; ++i) {
        int4 v = src[(size_t)i * 256 + t];
        atomicAdd(&hist[v.x], 1); atomicAdd(&hist[v.y], 1);
        atomicAdd(&hist[v.z], 1); atomicAdd(&hist[v.w], 1);
    }
    __syncthreads();
    #pragma unroll
    for (int i = 0; i < 4; ++i) {
        int k = t + i * 256;
        int c = hist[k];
        if (c) atomicAdd(&counts[k], c);
    }
}

// ---------------- K2: merged tail — rep compose + recon + MSE + partials ----
__global__ __launch_bounds__(256, 8)
void dl_tail(const float* __restrict__ x, const float* __restrict__ dict,
             const int* __restrict__ ws_sel, const float* __restrict__ ws_selp,
             float* __restrict__ out, float2* __restrict__ ws_lr)
{
    __shared__ float redL[4], redR[4];
    const int t = threadIdx.x;
    const int row = t >> 5, lr = t & 31;
    const size_t n = (size_t)blockIdx.x * 8 + row;

    int4 i0 = *(const int4*)(ws_sel + n * 8);
    int4 i1 = *(const int4*)(ws_sel + n * 8 + 4);
    const int idxs[8] = {i0.x, i0.y, i0.z, i0.w, i1.x, i1.y, i1.z, i1.w};
    float4 p0 = *(const float4*)(ws_selp + n * 8);
    float4 p1 = *(const float4*)(ws_selp + n * 8 + 4);
    const float p[8] = {p0.x, p0.y, p0.z, p0.w, p1.x, p1.y, p1.z, p1.w};

    // rep row: register-composed dense float4s, coalesced nt stores (8/thread)
    float* rr = out + 2 + (size_t)NELEM + (n << 10);
    #pragma unroll
    for (int q = 0; q < 8; ++q) {
        const int c0 = (q * 32 + lr) * 4;
        f32x4 v = {0.f, 0.f, 0.f, 0.f};
        #pragma unroll
        for (int j = 0; j < 8; ++j) {
            const int d = idxs[j] - c0;
            v[0] = (d == 0) ? p[j] : v[0];
            v[1] = (d == 1) ? p[j] : v[1];
            v[2] = (d == 2) ? p[j] : v[2];
            v[3] = (d == 3) ? p[j] : v[3];
        }
        __builtin_nontemporal_store(v, (f32x4*)(rr + c0));
    }

    // recon + fused MSE (flat .view semantics: raw-order x is correct here)
    float4 z4 = make_float4(0.f, 0.f, 0.f, 0.f);
    const float4* xp = (const float4*)(x + (n << 8)) + lr * 2;
    float4 xA = xp[0], xB = xp[1];
    float4 aA = z4, aB = z4;
    #pragma unroll
    for (int j = 0; j < 8; ++j) {
        const float4* dp = (const float4*)(dict + ((size_t)idxs[j] << 8)) + lr * 2;
        float4 dA = dp[0], dB = dp[1];
        aA.x += p[j] * dA.x; aA.y += p[j] * dA.y;
        aA.z += p[j] * dA.z; aA.w += p[j] * dA.w;
        aB.x += p[j] * dB.x; aB.y += p[j] * dB.y;
        aB.z += p[j] * dB.z; aB.w += p[j] * dB.w;
    }
    float* ro = out + 1 + (n << 8) + lr * 8;
    __builtin_nontemporal_store(__builtin_bit_cast(f32x4, aA), (f32x4*)ro);
    __builtin_nontemporal_store(__builtin_bit_cast(f32x4, aB), (f32x4*)(ro + 4));
    float e0 = xA.x - aA.x, e1 = xA.y - aA.y, e2 = xA.z - aA.z, e3 = xA.w - aA.w;
    float e4 = xB.x - aB.x, e5 = xB.y - aB.y, e6 = xB.z - aB.z, e7 = xB.w - aB.w;
    float lsum = ((e0*e0 + e1*e1) + (e2*e2 + e3*e3))
               + ((e4*e4 + e5*e5) + (e6*e6 + e7*e7));
    float rsum = 0.f;
    if (lr == 0) {
        #pragma unroll
        for (int j = 0; j < 8; ++j) rsum += p[j];
    }

    #pragma unroll
    for (int off = 32; off; off >>= 1) {
        lsum += __shfl_down(lsum, off);
        rsum += __shfl_down(rsum, off);
    }
    if ((t & 63) == 0) { redL[t >> 6] = lsum; redR[t >> 6] = rsum; }
    __syncthreads();
    if (t == 0) {
        ws_lr[blockIdx.x] = make_float2(
            (redL[0] + redL[1]) + (redL[2] + redL[3]),
            (redR[0] + redR[1]) + (redR[2] + redR[3]));
    }
}

// ---------------- finalize scalars ------------------------------------------
__global__ void dl_final(const float2* __restrict__ ws_lr,
                         const int* __restrict__ counts,
                         float* __restrict__ out)
{
    __shared__ float re[4], rl[4], rr[4];
    int t = threadIdx.x;
    float e = 0.f;
    for (int k = t; k < KDIM; k += 256) {
        float p = (float)counts[k] * (1.0f / 524288.0f);
        e += p * logf(p + 1e-10f);
    }
    float ls = 0.f, rs = 0.f;
    for (int i = t; i < 8192; i += 256) {
        float2 v = ws_lr[i];
        ls += v.x; rs += v.y;
    }
    #pragma unroll
    for (int off = 32; off; off >>= 1) {
        e += __shfl_down(e, off);
        ls += __shfl_down(ls, off);
        rs += __shfl_down(rs, off);
    }
    if ((t & 63) == 0) { re[t >> 6] = e; rl[t >> 6] = ls; rr[t >> 6] = rs; }
    __syncthreads();
    if (t == 0) {
        float et = (re[0] + re[1]) + (re[2] + re[3]);
        out[(size_t)NELEM + 1] = __expf(-et);                     // perplexity
        out[0] = 2.0f * ((rl[0] + rl[1]) + (rl[2] + rl[3])) / (float)NELEM
               + ((rr[0] + rr[1]) + (rr[2] + rr[3]));             // loss + reg
    }
}

extern "C" void kernel_launch(void* const* d_in, const int* in_sizes, int n_in,
                              void* d_out, int out_size, void* d_ws, size_t ws_size,
                              hipStream_t stream) {
    const float* x    = (const float*)d_in[0];
    const float* dict = (const float*)d_in[1];
    const float* Wm   = (const float*)d_in[2];
    const float* bv   = (const float*)d_in[3];
    float* out = (float*)d_out;

    int*    counts  = (int*)((char*)d_ws + WS_COUNTS);
    float*  dn      = (float*)((char*)d_ws + WS_DN);
    float*  b2      = (float*)((char*)d_ws + WS_B2);
    u16*    WhT     = (u16*)((char*)d_ws + WS_WH);
    u16*    DhT     = (u16*)((char*)d_ws + WS_DH);
    int*    ws_sel  = (int*)((char*)d_ws + WS_SEL);
    float*  ws_selp = (float*)((char*)d_ws + WS_SELP);
    float2* ws_lr   = (float2*)((char*)d_ws + WS_LR);

    hipMemsetAsync(d_ws, 0, 4608, stream);
    dl_prep<<<KDIM, 256, 0, stream>>>(Wm, dict, bv, WhT, DhT, dn, b2);
    dl_main<<<65536 / MROWS, 512, 0, stream>>>(x, Wm, bv, WhT, DhT, dn, b2,
                                               ws_sel, ws_selp);
    dl_count<<<64, 256, 0, stream>>>(ws_sel, counts);
    dl_tail<<<65536 / 8, 256, 0, stream>>>(x, dict, ws_sel, ws_selp, out, ws_lr);
    dl_final<<<1, 256, 0, stream>>>(ws_lr, counts, out);
}

// Round 19
// 319.389 us; speedup vs baseline: 1.0966x; 1.0098x over previous
//
#include <hip/hip_runtime.h>
#include <math.h>

#define CDIM 256
#define KDIM 1024
#define TOPK 8
#define MROWS 32
#define NELEM 16777216
#define L2E 1.4426950408889634f

typedef unsigned short u16;
typedef unsigned int u32;
typedef __attribute__((ext_vector_type(8))) short s16x8;
typedef __attribute__((ext_vector_type(8))) __bf16 b16x8;
typedef __attribute__((ext_vector_type(16))) float f32x16;
typedef __attribute__((ext_vector_type(4))) float f32x4;

#define ZERO16 {0.f,0.f,0.f,0.f,0.f,0.f,0.f,0.f,0.f,0.f,0.f,0.f,0.f,0.f,0.f,0.f}

// ws layout (bytes)
#define WS_COUNTS 64
#define WS_DN     4608
#define WS_B2     8704
#define WS_WH     16384                     // WhT: fragment-transposed, 512KB
#define WS_DH     (WS_WH + 524288)          // DhT: fragment-transposed, 512KB
#define WS_SEL    1064960                   // int[65536*8]   = 2 MB
#define WS_SELP   (WS_SEL + 2097152)        // float[65536*8] = 2 MB
#define WS_LR     (WS_SELP + 2097152)       // float2[8192]   = 64 KB

// K1 smem layout (bytes); overlays on xl/b2/dn after the main loop.
// xh/xl FRAGMENT-LINEAR: fragment f of row r at byte (f*32+r)*16, dims [8f,8f+8)
#define SM_XH   0        // 16K (LIVE through p-recompute)
#define SM_XL   16384    // 16K
#define SM_B2   32768    // 4K
#define SM_DN   36864    // 4K
#define SM_TOT  40960
#define SM_PD   16384    // 8K over xl
#define SM_PI   24576    // 8K over xl
#define SM_PM   32768    // 1K over b2
#define SM_PS   33792    // 1K over b2
#define SM_SELI 36864    // 1K over dn
#define SM_SELM 37888    // 128B over dn
#define SM_SELS 38016    // 128B over dn

__device__ __forceinline__ u16 f2bf(float f) {
    u32 u = __builtin_bit_cast(u32, f);
    u += 0x7FFFu + ((u >> 16) & 1u);
    return (u16)(u >> 16);
}
__device__ __forceinline__ float bf2f(u16 h) {
    return __builtin_bit_cast(float, ((u32)h) << 16);
}
__device__ __forceinline__ float hi2f(u32 u) {
    return __builtin_bit_cast(float, u & 0xFFFF0000u);
}
__device__ __forceinline__ f32x16 mfma16(s16x8 a, s16x8 b, f32x16 c) {
    return __builtin_amdgcn_mfma_f32_32x32x16_bf16(
        __builtin_bit_cast(b16x8, a), __builtin_bit_cast(b16x8, b), c, 0, 0, 0);
}
__device__ __forceinline__ u32 mono(float f) {
    u32 u = __builtin_bit_cast(u32, f);
    int m = (int)u >> 31;
    return u ^ (u32)(m | (int)0x80000000);
}
__device__ __forceinline__ float unmono(u32 v) {
    int m = (int)v >> 31;
    return __builtin_bit_cast(float, v ^ (u32)((int)0x80000000 | ~m));
}

// compare-exchange on packed u32 keys: v_min_u32 + v_max_u32
#define CEK(K, A, B) { u32 lo_ = min(K[A], K[B]); u32 hi_ = max(K[A], K[B]); \
                       K[A] = lo_; K[B] = hi_; }

// 4-wide batch insert: sort c[0..3], then bitonic-merge into sorted hk[0..7].
// Produces EXACTLY the same top-8 set as 4 sequential sorted inserts.
#define MERGE4(HK, C) { \
    CEK(C,0,1) CEK(C,2,3) CEK(C,0,2) CEK(C,1,3) CEK(C,1,2) \
    HK[4] = min(HK[4], C[3]); HK[5] = min(HK[5], C[2]); \
    HK[6] = min(HK[6], C[1]); HK[7] = min(HK[7], C[0]); \
    CEK(HK,0,4) CEK(HK,1,5) CEK(HK,2,6) CEK(HK,3,7) \
    CEK(HK,0,2) CEK(HK,1,3) CEK(HK,4,6) CEK(HK,5,7) \
    CEK(HK,0,1) CEK(HK,2,3) CEK(HK,4,5) CEK(HK,6,7) }

#define CE(HD, HX, A, B) { \
    bool sw_ = (HD[B] < HD[A]) || (HD[B] == HD[A] && HX[B] < HX[A]); \
    if (sw_) { float td_ = HD[A]; HD[A] = HD[B]; HD[B] = td_; \
               int ti_ = HX[A]; HX[A] = HX[B]; HX[B] = ti_; } }

#define MERGE8(HD, HX, OD, OI) { \
    _Pragma("unroll") \
    for (int j_ = 0; j_ < 8; ++j_) { \
        float bd_ = OD[7 - j_]; int bi_ = OI[7 - j_]; \
        if (bd_ < HD[j_] || (bd_ == HD[j_] && bi_ < HX[j_])) { \
            HD[j_] = bd_; HX[j_] = bi_; } } \
    CE(HD,HX,0,4) CE(HD,HX,1,5) CE(HD,HX,2,6) CE(HD,HX,3,7) \
    CE(HD,HX,0,2) CE(HD,HX,1,3) CE(HD,HX,4,6) CE(HD,HX,5,7) \
    CE(HD,HX,0,1) CE(HD,HX,2,3) CE(HD,HX,4,5) CE(HD,HX,6,7) }

#define SMAX_TILE(ACC, MM, SS) { \
    float lv_[16]; \
    _Pragma("unroll") \
    for (int rg_ = 0; rg_ < 4; ++rg_) { \
        lv_[4*rg_+0] = ACC[4*rg_+0] + bv4[rg_].x; \
        lv_[4*rg_+1] = ACC[4*rg_+1] + bv4[rg_].y; \
        lv_[4*rg_+2] = ACC[4*rg_+2] + bv4[rg_].z; \
        lv_[4*rg_+3] = ACC[4*rg_+3] + bv4[rg_].w; } \
    float x0_ = fmaxf(lv_[0],lv_[1]),  x1_ = fmaxf(lv_[2],lv_[3]); \
    float x2_ = fmaxf(lv_[4],lv_[5]),  x3_ = fmaxf(lv_[6],lv_[7]); \
    float x4_ = fmaxf(lv_[8],lv_[9]),  x5_ = fmaxf(lv_[10],lv_[11]); \
    float x6_ = fmaxf(lv_[12],lv_[13]), x7_ = fmaxf(lv_[14],lv_[15]); \
    x0_ = fmaxf(x0_,x1_); x2_ = fmaxf(x2_,x3_); \
    x4_ = fmaxf(x4_,x5_); x6_ = fmaxf(x6_,x7_); \
    float mn_ = fmaxf(fmaxf(fmaxf(x0_,x2_), fmaxf(x4_,x6_)), MM); \
    float e0_ = exp2f(lv_[0]-mn_) + exp2f(lv_[1]-mn_); \
    float e1_ = exp2f(lv_[2]-mn_) + exp2f(lv_[3]-mn_); \
    float e2_ = exp2f(lv_[4]-mn_) + exp2f(lv_[5]-mn_); \
    float e3_ = exp2f(lv_[6]-mn_) + exp2f(lv_[7]-mn_); \
    float e4_ = exp2f(lv_[8]-mn_) + exp2f(lv_[9]-mn_); \
    float e5_ = exp2f(lv_[10]-mn_) + exp2f(lv_[11]-mn_); \
    float e6_ = exp2f(lv_[12]-mn_) + exp2f(lv_[13]-mn_); \
    float e7_ = exp2f(lv_[14]-mn_) + exp2f(lv_[15]-mn_); \
    float sa_ = ((e0_+e1_) + (e2_+e3_)) + ((e4_+e5_) + (e6_+e7_)); \
    SS = SS * exp2f(MM - mn_) + sa_; MM = mn_; }

// ---------------- prepass: bf16 splits into FRAGMENT-TRANSPOSED layout ------
__global__ __launch_bounds__(256)
void dl_prep(const float* __restrict__ Wm, const float* __restrict__ dict,
             const float* __restrict__ bv,
             u16* __restrict__ WhT, u16* __restrict__ DhT,
             float* __restrict__ dn, float* __restrict__ b2)
{
    __shared__ float red[4];
    const int k = blockIdx.x, c = threadIdx.x;
    const size_t idx = ((size_t)k << 8) + c;
    const size_t dst = ((((size_t)(k >> 5) * 16 + (c >> 4)) * 64)
                        + (((c >> 3) & 1) << 5) + (k & 31)) * 8 + (c & 7);
    WhT[dst] = f2bf(Wm[idx] * L2E);
    float d = dict[idx];
    DhT[dst] = f2bf(-2.0f * d);
    float sq = d * d;
    #pragma unroll
    for (int off = 32; off; off >>= 1) sq += __shfl_down(sq, off);
    if ((c & 63) == 0) red[c >> 6] = sq;
    __syncthreads();
    if (c == 0) { dn[k] = red[0] + red[1] + red[2] + red[3]; b2[k] = bv[k] * L2E; }
}

// ---------------- K1: selection + probabilities (merged L+D phase) ----------
__global__ __launch_bounds__(512, 6)
void dl_main(const float* __restrict__ x, const float* __restrict__ Wm,
             const float* __restrict__ bv, const u16* __restrict__ WhT,
             const u16* __restrict__ DhT, const float* __restrict__ dnp,
             const float* __restrict__ b2g,
             int* __restrict__ ws_sel, float* __restrict__ ws_selp)
{
    __shared__ __align__(16) char smem[SM_TOT];
    u16*   xh   = (u16*)(smem + SM_XH);
    u16*   xl   = (u16*)(smem + SM_XL);
    float* b2_s = (float*)(smem + SM_B2);
    float* dn_s = (float*)(smem + SM_DN);
    float* pd   = (float*)(smem + SM_PD);
    int*   pi   = (int*)(smem + SM_PI);
    float* pm   = (float*)(smem + SM_PM);
    float* ps   = (float*)(smem + SM_PS);
    int*   seli = (int*)(smem + SM_SELI);
    float* selm = (float*)(smem + SM_SELM);
    float* sels = (float*)(smem + SM_SELS);

    const int t = threadIdx.x;
    const int lane = t & 63;
    const int wid = t >> 6;
    const int n0 = blockIdx.x * MROWS;

    // ---- stage x -> bf16 hi/lo in FRAGMENT-LINEAR layout (write addr = t*16)
    {
        const int r = t & 31;
        const float* xb = x + ((size_t)(n0 >> 12) << 20) + (n0 & 4095) + r;
        #pragma unroll
        for (int gg = 0; gg < 2; ++gg) {
            const int f = (t >> 5) + gg * 16;     // fragment id, dims [8f,8f+8)
            const int c0 = f * 8;
            u32 hw[4], lw[4];
            #pragma unroll
            for (int i = 0; i < 8; i += 2) {
                float a0 = xb[(size_t)(c0 + i) << 12];
                float a1 = xb[(size_t)(c0 + i + 1) << 12];
                u16 h0 = f2bf(a0), h1 = f2bf(a1);
                u16 e0 = f2bf(a0 - bf2f(h0)), e1 = f2bf(a1 - bf2f(h1));
                hw[i >> 1] = (u32)h0 | ((u32)h1 << 16);
                lw[i >> 1] = (u32)e0 | ((u32)e1 << 16);
            }
            const int byte = (f * 32 + r) * 16;   // == (t + gg*512)*16, linear
            *(uint4*)((char*)xh + byte) = make_uint4(hw[0], hw[1], hw[2], hw[3]);
            *(uint4*)((char*)xl + byte) = make_uint4(lw[0], lw[1], lw[2], lw[3]);
        }
        b2_s[t] = b2g[t];  b2_s[512 + t] = b2g[512 + t];
        dn_s[t] = dnp[t];  dn_s[512 + t] = dnp[512 + t];
    }
    __syncthreads();

    const int arow = lane & 31, hl = lane >> 5;

    float m0 = -INFINITY, s0 = 0.f;
    u32 hk0[TOPK];
    #pragma unroll
    for (int j = 0; j < TOPK; ++j) hk0[j] = 0xFFFFFFFFu;

    // ---- barrier-free main loop: 4 chunks of 256 atoms, SINGLE merged phase
    //      per chunk (W and D loads + all 3 MFMAs interleaved: 2x MLP, half
    //      the serial wait-points vs split phases)
    #pragma unroll 1
    for (int ck = 0; ck < 4; ++ck) {
        const int ab = ck * 8 + wid;          // atom block: atoms [ab*32, +32)
        const u16* Wp = WhT + ((size_t)ab << 13) + (lane << 3);
        const u16* Dp = DhT + ((size_t)ab << 13) + (lane << 3);
        const int cb = (ck << 8) + (wid << 5) + (hl << 2);

        f32x16 accL = ZERO16, accD = ZERO16;
        __builtin_amdgcn_s_setprio(1);
        #pragma unroll 2
        for (int kst = 0; kst < 16; ++kst) {
            int bo = kst * 1024 + lane * 16;
            s16x8 aw  = *(const s16x8*)(Wp + kst * 512);
            s16x8 adh = *(const s16x8*)(Dp + kst * 512);
            s16x8 bh = *(const s16x8*)((const char*)xh + bo);
            s16x8 bl = *(const s16x8*)((const char*)xl + bo);
            accL = mfma16(aw,  bh, accL);
            accD = mfma16(adh, bh, accD);
            accD = mfma16(adh, bl, accD);
        }
        __builtin_amdgcn_s_setprio(0);

        float4 bv4[4];
        #pragma unroll
        for (int rg = 0; rg < 4; ++rg)
            bv4[rg] = *(const float4*)(b2_s + cb + rg * 8);
        SMAX_TILE(accL, m0, s0)

        float4 n44[4];
        #pragma unroll
        for (int rg = 0; rg < 4; ++rg)
            n44[rg] = *(const float4*)(dn_s + cb + rg * 8);
        const u32 ob = (u32)(ck << 4);
        #pragma unroll
        for (int rg = 0; rg < 4; ++rg) {
            const u32 o0 = ob + rg * 4;
            u32 c[4];
            c[0] = (mono(n44[rg].x + accD[4*rg+0]) & ~63u) | (o0 + 0);
            c[1] = (mono(n44[rg].y + accD[4*rg+1]) & ~63u) | (o0 + 1);
            c[2] = (mono(n44[rg].z + accD[4*rg+2]) & ~63u) | (o0 + 2);
            c[3] = (mono(n44[rg].w + accD[4*rg+3]) & ~63u) | (o0 + 3);
            MERGE4(hk0, c)
        }
    }

    // ---- decode packed keys -> (dist, global atom idx)
    float hd0[TOPK];
    int hix0[TOPK];
    #pragma unroll
    for (int j = 0; j < TOPK; ++j) {
        u32 v = hk0[j]; int o = (int)(v & 63u);
        hd0[j] = unmono(v & ~63u);
        hix0[j] = ((o >> 4) << 8) + (wid << 5) + (((o >> 2) & 3) << 3) + (hl << 2) + (o & 3);
    }

    // ---- intra-wave merge (lane n <-> n+32)
    {
        float mo = __shfl_xor(m0, 32), so = __shfl_xor(s0, 32);
        float mn = fmaxf(m0, mo);
        s0 = s0 * exp2f(m0 - mn) + so * exp2f(mo - mn);
        m0 = mn;
        float od[TOPK]; int oi[TOPK];
        #pragma unroll
        for (int j = 0; j < TOPK; ++j) {
            od[j] = __shfl_xor(hd0[j], 32); oi[j] = __shfl_xor(hix0[j], 32);
        }
        MERGE8(hd0, hix0, od, oi)
    }

    // ---- publish the 8 wave-lists per row (overlay on dead xl/b2)
    __syncthreads();
    if (lane < 32) {
        const int base = arow * 64 + wid * 8;
        #pragma unroll
        for (int j = 0; j < TOPK; ++j) { pd[base + j] = hd0[j]; pi[base + j] = hix0[j]; }
        pm[arow * 8 + wid] = m0; ps[arow * 8 + wid] = s0;
    }
    __syncthreads();

    // ---- final merge (8 threads/row) -> seli/selm/sels (LDS) + ws_sel
    if (t < 256) {
        const int row = t >> 3, src = t & 7;
        float hd[TOPK]; int hix[TOPK];
        #pragma unroll
        for (int j = 0; j < TOPK; ++j) {
            hd[j] = pd[row * 64 + src * 8 + j];
            hix[j] = pi[row * 64 + src * 8 + j];
        }
        float m = pm[row * 8 + src], s = ps[row * 8 + src];
        #pragma unroll
        for (int k = 1; k <= 4; k <<= 1) {
            float mo = __shfl_xor(m, k), so = __shfl_xor(s, k);
            float mn = fmaxf(m, mo);
            s = s * exp2f(m - mn) + so * exp2f(mo - mn);
            m = mn;
            float od[TOPK]; int oi[TOPK];
            #pragma unroll
            for (int j = 0; j < TOPK; ++j) {
                od[j] = __shfl_xor(hd[j], k); oi[j] = __shfl_xor(hix[j], k);
            }
            MERGE8(hd, hix, od, oi)
        }
        if (src == 0) {
            size_t n = (size_t)(n0 + row);
            selm[row] = m;
            sels[row] = 1.0f / s;
            #pragma unroll
            for (int j = 0; j < TOPK; ++j) seli[row * 8 + j] = hix[j];
            *(int4*)(ws_sel + n * 8)     = make_int4(hix[0], hix[1], hix[2], hix[3]);
            *(int4*)(ws_sel + n * 8 + 4) = make_int4(hix[4], hix[5], hix[6], hix[7]);
        }
    }
    __syncthreads();

    // ---- recompute winner logits from LDS xh (true x_flat rows) + fp32 W, b
    {
        const int row = t >> 4, j = (t >> 1) & 7, half = t & 1;
        const int idxw = seli[row * 8 + j];
        const float4* wp = (const float4*)(Wm + ((size_t)idxw << 8)) + half * 32;
        float ax = 0.f, ay = 0.f, az = 0.f, aw2 = 0.f;
        #pragma unroll 8
        for (int i = 0; i < 16; ++i) {
            const int byte = ((half * 16 + i) * 32 + row) * 16;  // fragment-linear
            uint4 H = *(const uint4*)((const char*)xh + byte);
            float4 w0 = wp[i * 2], w1 = wp[i * 2 + 1];
            ax += bf2f((u16)H.x) * w0.x; ay += hi2f(H.x) * w0.y;
            az += bf2f((u16)H.y) * w0.z; aw2 += hi2f(H.y) * w0.w;
            ax += bf2f((u16)H.z) * w1.x; ay += hi2f(H.z) * w1.y;
            az += bf2f((u16)H.w) * w1.z; aw2 += hi2f(H.w) * w1.w;
        }
        float a = (ax + ay) + (az + aw2);
        a += __shfl_xor(a, 1);
        if (half == 0) {
            float p = exp2f((a + bv[idxw]) * L2E - selm[row]) * sels[row];
            ws_selp[(size_t)(n0 + row) * 8 + j] = p;
        }
    }
}

// ---------------- K2c: counts via LDS histogram (skew-proof) ----------------
__global__ __launch_bounds__(256)
void dl_count(const int* __restrict__ ws_sel, int* __restrict__ counts)
{
    __shared__ int hist[KDIM];
    const int t = threadIdx.x;
    #pragma unroll
    for (int i = 0; i < 4; ++i) hist[t + i * 256] = 0;
    __syncthreads();
    const int4* src = (const int4*)(ws_sel + (size_t)blockIdx.x * 8192);
    #pragma unroll
    for (int i = 0; i < 8; ++i) {
        int4 v = src[(size_t)i * 256 + t];
        atomicAdd(&hist[v.x], 1); atomicAdd(&hist[v.y], 1);
        atomicAdd(&hist[v.z], 1); atomicAdd(&hist[v.w], 1);
    }
    __syncthreads();
    #pragma unroll
    for (int i = 0; i < 4; ++i) {
        int k = t + i * 256;
        int c = hist[k];
        if (c) atomicAdd(&counts[k], c);
    }
}

// ---------------- K2: merged tail — rep compose + recon + MSE + partials ----
__global__ __launch_bounds__(256, 8)
void dl_tail(const float* __restrict__ x, const float* __restrict__ dict,
             const int* __restrict__ ws_sel, const float* __restrict__ ws_selp,
             float* __restrict__ out, float2* __restrict__ ws_lr)
{
    __shared__ float redL[4], redR[4];
    const int t = threadIdx.x;
    const int row = t >> 5, lr = t & 31;
    const size_t n = (size_t)blockIdx.x * 8 + row;

    int4 i0 = *(const int4*)(ws_sel + n * 8);
    int4 i1 = *(const int4*)(ws_sel + n * 8 + 4);
    const int idxs[8] = {i0.x, i0.y, i0.z, i0.w, i1.x, i1.y, i1.z, i1.w};
    float4 p0 = *(const float4*)(ws_selp + n * 8);
    float4 p1 = *(const float4*)(ws_selp + n * 8 + 4);
    const float p[8] = {p0.x, p0.y, p0.z, p0.w, p1.x, p1.y, p1.z, p1.w};

    // rep row: register-composed dense float4s, coalesced nt stores (8/thread)
    float* rr = out + 2 + (size_t)NELEM + (n << 10);
    #pragma unroll
    for (int q = 0; q < 8; ++q) {
        const int c0 = (q * 32 + lr) * 4;
        f32x4 v = {0.f, 0.f, 0.f, 0.f};
        #pragma unroll
        for (int j = 0; j < 8; ++j) {
            const int d = idxs[j] - c0;
            v[0] = (d == 0) ? p[j] : v[0];
            v[1] = (d == 1) ? p[j] : v[1];
            v[2] = (d == 2) ? p[j] : v[2];
            v[3] = (d == 3) ? p[j] : v[3];
        }
        __builtin_nontemporal_store(v, (f32x4*)(rr + c0));
    }

    // recon + fused MSE (flat .view semantics: raw-order x is correct here)
    float4 z4 = make_float4(0.f, 0.f, 0.f, 0.f);
    const float4* xp = (const float4*)(x + (n << 8)) + lr * 2;
    float4 xA = xp[0], xB = xp[1];
    float4 aA = z4, aB = z4;
    #pragma unroll
    for (int j = 0; j < 8; ++j) {
        const float4* dp = (const float4*)(dict + ((size_t)idxs[j] << 8)) + lr * 2;
        float4 dA = dp[0], dB = dp[1];
        aA.x += p[j] * dA.x; aA.y += p[j] * dA.y;
        aA.z += p[j] * dA.z; aA.w += p[j] * dA.w;
        aB.x += p[j] * dB.x; aB.y += p[j] * dB.y;
        aB.z += p[j] * dB.z; aB.w += p[j] * dB.w;
    }
    float* ro = out + 1 + (n << 8) + lr * 8;
    __builtin_nontemporal_store(__builtin_bit_cast(f32x4, aA), (f32x4*)ro);
    __builtin_nontemporal_store(__builtin_bit_cast(f32x4, aB), (f32x4*)(ro + 4));
    float e0 = xA.x - aA.x, e1 = xA.y - aA.y, e2 = xA.z - aA.z, e3 = xA.w - aA.w;
    float e4 = xB.x - aB.x, e5 = xB.y - aB.y, e6 = xB.z - aB.z, e7 = xB.w - aB.w;
    float lsum = ((e0*e0 + e1*e1) + (e2*e2 + e3*e3))
               + ((e4*e4 + e5*e5) + (e6*e6 + e7*e7));
    float rsum = 0.f;
    if (lr == 0) {
        #pragma unroll
        for (int j = 0; j < 8; ++j) rsum += p[j];
    }

    #pragma unroll
    for (int off = 32; off; off >>= 1) {
        lsum += __shfl_down(lsum, off);
        rsum += __shfl_down(rsum, off);
    }
    if ((t & 63) == 0) { redL[t >> 6] = lsum; redR[t >> 6] = rsum; }
    __syncthreads();
    if (t == 0) {
        ws_lr[blockIdx.x] = make_float2(
            (redL[0] + redL[1]) + (redL[2] + redL[3]),
            (redR[0] + redR[1]) + (redR[2] + redR[3]));
    }
}

// ---------------- finalize scalars ------------------------------------------
__global__ void dl_final(const float2* __restrict__ ws_lr,
                         const int* __restrict__ counts,
                         float* __restrict__ out)
{
    __shared__ float re[4], rl[4], rr[4];
    int t = threadIdx.x;
    float e = 0.f;
    for (int k = t; k < KDIM; k += 256) {
        float p = (float)counts[k] * (1.0f / 524288.0f);
        e += p * logf(p + 1e-10f);
    }
    float ls = 0.f, rs = 0.f;
    for (int i = t; i < 8192; i += 256) {
        float2 v = ws_lr[i];
        ls += v.x; rs += v.y;
    }
    #pragma unroll
    for (int off = 32; off; off >>= 1) {
        e += __shfl_down(e, off);
        ls += __shfl_down(ls, off);
        rs += __shfl_down(rs, off);
    }
    if ((t & 63) == 0) { re[t >> 6] = e; rl[t >> 6] = ls; rr[t >> 6] = rs; }
    __syncthreads();
    if (t == 0) {
        float et = (re[0] + re[1]) + (re[2] + re[3]);
        out[(size_t)NELEM + 1] = __expf(-et);                     // perplexity
        out[0] = 2.0f * ((rl[0] + rl[1]) + (rl[2] + rl[3])) / (float)NELEM
               + ((rr[0] + rr[1]) + (rr[2] + rr[3]));             // loss + reg
    }
}

extern "C" void kernel_launch(void* const* d_in, const int* in_sizes, int n_in,
                              void* d_out, int out_size, void* d_ws, size_t ws_size,
                              hipStream_t stream) {
    const float* x    = (const float*)d_in[0];
    const float* dict = (const float*)d_in[1];
    const float* Wm   = (const float*)d_in[2];
    const float* bv   = (const float*)d_in[3];
    float* out = (float*)d_out;

    int*    counts  = (int*)((char*)d_ws + WS_COUNTS);
    float*  dn      = (float*)((char*)d_ws + WS_DN);
    float*  b2      = (float*)((char*)d_ws + WS_B2);
    u16*    WhT     = (u16*)((char*)d_ws + WS_WH);
    u16*    DhT     = (u16*)((char*)d_ws + WS_DH);
    int*    ws_sel  = (int*)((char*)d_ws + WS_SEL);
    float*  ws_selp = (float*)((char*)d_ws + WS_SELP);
    float2* ws_lr   = (float2*)((char*)d_ws + WS_LR);

    hipMemsetAsync(d_ws, 0, 4608, stream);
    dl_prep<<<KDIM, 256, 0, stream>>>(Wm, dict, bv, WhT, DhT, dn, b2);
    dl_main<<<65536 / MROWS, 512, 0, stream>>>(x, Wm, bv, WhT, DhT, dn, b2,
                                               ws_sel, ws_selp);
    dl_count<<<64, 256, 0, stream>>>(ws_sel, counts);
    dl_tail<<<65536 / 8, 256, 0, stream>>>(x, dict, ws_sel, ws_selp, out, ws_lr);
    dl_final<<<1, 256, 0, stream>>>(ws_lr, counts, out);
}

// Round 20
// 289.922 us; speedup vs baseline: 1.2080x; 1.1016x over previous
//
#include <hip/hip_runtime.h>
#include <math.h>

#define CDIM 256
#define KDIM 1024
#define TOPK 8
#define MROWS 32
#define NELEM 16777216
#define L2E 1.4426950408889634f

typedef unsigned short u16;
typedef unsigned int u32;
typedef __attribute__((ext_vector_type(8))) short s16x8;
typedef __attribute__((ext_vector_type(8))) __bf16 b16x8;
typedef __attribute__((ext_vector_type(16))) float f32x16;
typedef __attribute__((ext_vector_type(4))) float f32x4;

#define ZERO16 {0.f,0.f,0.f,0.f,0.f,0.f,0.f,0.f,0.f,0.f,0.f,0.f,0.f,0.f,0.f,0.f}

// ws layout (bytes)
#define WS_COUNTS 64
#define WS_DN     4608
#define WS_B2     8704
#define WS_WH     16384                     // WhT: fragment-transposed, 512KB
#define WS_DH     (WS_WH + 524288)          // DhT: fragment-transposed, 512KB
#define WS_SEL    1064960                   // int[65536*8]   = 2 MB
#define WS_SELP   (WS_SEL + 2097152)        // float[65536*8] = 2 MB
#define WS_LR     (WS_SELP + 2097152)       // float2[8192]   = 64 KB

// K1 smem layout (bytes). xh FRAGMENT-LINEAR: fragment f of row r at byte
// (f*32+r)*16, dims [8f,8f+8). [16K,32K) is merge-overlay scratch only.
#define SM_XH   0        // 16K (LIVE through p-recompute)
#define SM_B2   32768    // 4K
#define SM_DN   36864    // 4K
#define SM_TOT  40960
#define SM_PD   16384    // 8K scratch
#define SM_PI   24576    // 8K scratch
#define SM_PM   32768    // 1K over b2
#define SM_PS   33792    // 1K over b2
#define SM_SELI 36864    // 1K over dn
#define SM_SELM 37888    // 128B over dn
#define SM_SELS 38016    // 128B over dn

__device__ __forceinline__ u16 f2bf(float f) {
    u32 u = __builtin_bit_cast(u32, f);
    u += 0x7FFFu + ((u >> 16) & 1u);
    return (u16)(u >> 16);
}
__device__ __forceinline__ float bf2f(u16 h) {
    return __builtin_bit_cast(float, ((u32)h) << 16);
}
__device__ __forceinline__ float hi2f(u32 u) {
    return __builtin_bit_cast(float, u & 0xFFFF0000u);
}
__device__ __forceinline__ f32x16 mfma16(s16x8 a, s16x8 b, f32x16 c) {
    return __builtin_amdgcn_mfma_f32_32x32x16_bf16(
        __builtin_bit_cast(b16x8, a), __builtin_bit_cast(b16x8, b), c, 0, 0, 0);
}
__device__ __forceinline__ u32 mono(float f) {
    u32 u = __builtin_bit_cast(u32, f);
    int m = (int)u >> 31;
    return u ^ (u32)(m | (int)0x80000000);
}
__device__ __forceinline__ float unmono(u32 v) {
    int m = (int)v >> 31;
    return __builtin_bit_cast(float, v ^ (u32)((int)0x80000000 | ~m));
}

// compare-exchange on packed u32 keys: v_min_u32 + v_max_u32
#define CEK(K, A, B) { u32 lo_ = min(K[A], K[B]); u32 hi_ = max(K[A], K[B]); \
                       K[A] = lo_; K[B] = hi_; }

// 4-wide batch insert: sort c[0..3], then bitonic-merge into sorted hk[0..7].
#define MERGE4(HK, C) { \
    CEK(C,0,1) CEK(C,2,3) CEK(C,0,2) CEK(C,1,3) CEK(C,1,2) \
    HK[4] = min(HK[4], C[3]); HK[5] = min(HK[5], C[2]); \
    HK[6] = min(HK[6], C[1]); HK[7] = min(HK[7], C[0]); \
    CEK(HK,0,4) CEK(HK,1,5) CEK(HK,2,6) CEK(HK,3,7) \
    CEK(HK,0,2) CEK(HK,1,3) CEK(HK,4,6) CEK(HK,5,7) \
    CEK(HK,0,1) CEK(HK,2,3) CEK(HK,4,5) CEK(HK,6,7) }

#define CE(HD, HX, A, B) { \
    bool sw_ = (HD[B] < HD[A]) || (HD[B] == HD[A] && HX[B] < HX[A]); \
    if (sw_) { float td_ = HD[A]; HD[A] = HD[B]; HD[B] = td_; \
               int ti_ = HX[A]; HX[A] = HX[B]; HX[B] = ti_; } }

#define MERGE8(HD, HX, OD, OI) { \
    _Pragma("unroll") \
    for (int j_ = 0; j_ < 8; ++j_) { \
        float bd_ = OD[7 - j_]; int bi_ = OI[7 - j_]; \
        if (bd_ < HD[j_] || (bd_ == HD[j_] && bi_ < HX[j_])) { \
            HD[j_] = bd_; HX[j_] = bi_; } } \
    CE(HD,HX,0,4) CE(HD,HX,1,5) CE(HD,HX,2,6) CE(HD,HX,3,7) \
    CE(HD,HX,0,2) CE(HD,HX,1,3) CE(HD,HX,4,6) CE(HD,HX,5,7) \
    CE(HD,HX,0,1) CE(HD,HX,2,3) CE(HD,HX,4,5) CE(HD,HX,6,7) }

#define SMAX_TILE(ACC, MM, SS) { \
    float lv_[16]; \
    _Pragma("unroll") \
    for (int rg_ = 0; rg_ < 4; ++rg_) { \
        lv_[4*rg_+0] = ACC[4*rg_+0] + bv4[rg_].x; \
        lv_[4*rg_+1] = ACC[4*rg_+1] + bv4[rg_].y; \
        lv_[4*rg_+2] = ACC[4*rg_+2] + bv4[rg_].z; \
        lv_[4*rg_+3] = ACC[4*rg_+3] + bv4[rg_].w; } \
    float x0_ = fmaxf(lv_[0],lv_[1]),  x1_ = fmaxf(lv_[2],lv_[3]); \
    float x2_ = fmaxf(lv_[4],lv_[5]),  x3_ = fmaxf(lv_[6],lv_[7]); \
    float x4_ = fmaxf(lv_[8],lv_[9]),  x5_ = fmaxf(lv_[10],lv_[11]); \
    float x6_ = fmaxf(lv_[12],lv_[13]), x7_ = fmaxf(lv_[14],lv_[15]); \
    x0_ = fmaxf(x0_,x1_); x2_ = fmaxf(x2_,x3_); \
    x4_ = fmaxf(x4_,x5_); x6_ = fmaxf(x6_,x7_); \
    float mn_ = fmaxf(fmaxf(fmaxf(x0_,x2_), fmaxf(x4_,x6_)), MM); \
    float e0_ = exp2f(lv_[0]-mn_) + exp2f(lv_[1]-mn_); \
    float e1_ = exp2f(lv_[2]-mn_) + exp2f(lv_[3]-mn_); \
    float e2_ = exp2f(lv_[4]-mn_) + exp2f(lv_[5]-mn_); \
    float e3_ = exp2f(lv_[6]-mn_) + exp2f(lv_[7]-mn_); \
    float e4_ = exp2f(lv_[8]-mn_) + exp2f(lv_[9]-mn_); \
    float e5_ = exp2f(lv_[10]-mn_) + exp2f(lv_[11]-mn_); \
    float e6_ = exp2f(lv_[12]-mn_) + exp2f(lv_[13]-mn_); \
    float e7_ = exp2f(lv_[14]-mn_) + exp2f(lv_[15]-mn_); \
    float sa_ = ((e0_+e1_) + (e2_+e3_)) + ((e4_+e5_) + (e6_+e7_)); \
    SS = SS * exp2f(MM - mn_) + sa_; MM = mn_; }

// ---------------- prepass: bf16 splits into FRAGMENT-TRANSPOSED layout ------
__global__ __launch_bounds__(256)
void dl_prep(const float* __restrict__ Wm, const float* __restrict__ dict,
             const float* __restrict__ bv,
             u16* __restrict__ WhT, u16* __restrict__ DhT,
             float* __restrict__ dn, float* __restrict__ b2)
{
    __shared__ float red[4];
    const int k = blockIdx.x, c = threadIdx.x;
    const size_t idx = ((size_t)k << 8) + c;
    const size_t dst = ((((size_t)(k >> 5) * 16 + (c >> 4)) * 64)
                        + (((c >> 3) & 1) << 5) + (k & 31)) * 8 + (c & 7);
    WhT[dst] = f2bf(Wm[idx] * L2E);
    float d = dict[idx];
    DhT[dst] = f2bf(-2.0f * d);
    float sq = d * d;
    #pragma unroll
    for (int off = 32; off; off >>= 1) sq += __shfl_down(sq, off);
    if ((c & 63) == 0) red[c >> 6] = sq;
    __syncthreads();
    if (c == 0) { dn[k] = red[0] + red[1] + red[2] + red[3]; b2[k] = bv[k] * L2E; }
}

// ---------------- K1: selection + probabilities (hi-only distance) ----------
__global__ __launch_bounds__(512, 6)
void dl_main(const float* __restrict__ x, const float* __restrict__ Wm,
             const float* __restrict__ bv, const u16* __restrict__ WhT,
             const u16* __restrict__ DhT, const float* __restrict__ dnp,
             const float* __restrict__ b2g,
             int* __restrict__ ws_sel, float* __restrict__ ws_selp)
{
    __shared__ __align__(16) char smem[SM_TOT];
    u16*   xh   = (u16*)(smem + SM_XH);
    float* b2_s = (float*)(smem + SM_B2);
    float* dn_s = (float*)(smem + SM_DN);
    float* pd   = (float*)(smem + SM_PD);
    int*   pi   = (int*)(smem + SM_PI);
    float* pm   = (float*)(smem + SM_PM);
    float* ps   = (float*)(smem + SM_PS);
    int*   seli = (int*)(smem + SM_SELI);
    float* selm = (float*)(smem + SM_SELM);
    float* sels = (float*)(smem + SM_SELS);

    const int t = threadIdx.x;
    const int lane = t & 63;
    const int wid = t >> 6;
    const int n0 = blockIdx.x * MROWS;

    // ---- stage x -> bf16 hi in FRAGMENT-LINEAR layout (write addr = t*16)
    {
        const int r = t & 31;
        const float* xb = x + ((size_t)(n0 >> 12) << 20) + (n0 & 4095) + r;
        #pragma unroll
        for (int gg = 0; gg < 2; ++gg) {
            const int f = (t >> 5) + gg * 16;     // fragment id, dims [8f,8f+8)
            const int c0 = f * 8;
            u32 hw[4];
            #pragma unroll
            for (int i = 0; i < 8; i += 2) {
                float a0 = xb[(size_t)(c0 + i) << 12];
                float a1 = xb[(size_t)(c0 + i + 1) << 12];
                hw[i >> 1] = (u32)f2bf(a0) | ((u32)f2bf(a1) << 16);
            }
            const int byte = (f * 32 + r) * 16;   // == (t + gg*512)*16, linear
            *(uint4*)((char*)xh + byte) = make_uint4(hw[0], hw[1], hw[2], hw[3]);
        }
        b2_s[t] = b2g[t];  b2_s[512 + t] = b2g[512 + t];
        dn_s[t] = dnp[t];  dn_s[512 + t] = dnp[512 + t];
    }
    __syncthreads();

    const int arow = lane & 31, hl = lane >> 5;

    float m0 = -INFINITY, s0 = 0.f;
    u32 hk0[TOPK];
    #pragma unroll
    for (int j = 0; j < TOPK; ++j) hk0[j] = 0xFFFFFFFFu;

    // ---- barrier-free main loop: 4 chunks of 256 atoms, single merged phase
    #pragma unroll 1
    for (int ck = 0; ck < 4; ++ck) {
        const int ab = ck * 8 + wid;          // atom block: atoms [ab*32, +32)
        const u16* Wp = WhT + ((size_t)ab << 13) + (lane << 3);
        const u16* Dp = DhT + ((size_t)ab << 13) + (lane << 3);
        const int cb = (ck << 8) + (wid << 5) + (hl << 2);

        f32x16 accL = ZERO16, accD = ZERO16;
        __builtin_amdgcn_s_setprio(1);
        #pragma unroll 2
        for (int kst = 0; kst < 16; ++kst) {
            int bo = kst * 1024 + lane * 16;
            s16x8 aw  = *(const s16x8*)(Wp + kst * 512);
            s16x8 adh = *(const s16x8*)(Dp + kst * 512);
            s16x8 bh = *(const s16x8*)((const char*)xh + bo);
            accL = mfma16(aw,  bh, accL);
            accD = mfma16(adh, bh, accD);
        }
        __builtin_amdgcn_s_setprio(0);

        float4 bv4[4];
        #pragma unroll
        for (int rg = 0; rg < 4; ++rg)
            bv4[rg] = *(const float4*)(b2_s + cb + rg * 8);
        SMAX_TILE(accL, m0, s0)

        float4 n44[4];
        #pragma unroll
        for (int rg = 0; rg < 4; ++rg)
            n44[rg] = *(const float4*)(dn_s + cb + rg * 8);
        const u32 ob = (u32)(ck << 4);
        #pragma unroll
        for (int rg = 0; rg < 4; ++rg) {
            const u32 o0 = ob + rg * 4;
            u32 c[4];
            c[0] = (mono(n44[rg].x + accD[4*rg+0]) & ~63u) | (o0 + 0);
            c[1] = (mono(n44[rg].y + accD[4*rg+1]) & ~63u) | (o0 + 1);
            c[2] = (mono(n44[rg].z + accD[4*rg+2]) & ~63u) | (o0 + 2);
            c[3] = (mono(n44[rg].w + accD[4*rg+3]) & ~63u) | (o0 + 3);
            MERGE4(hk0, c)
        }
    }

    // ---- decode packed keys -> (dist, global atom idx)
    float hd0[TOPK];
    int hix0[TOPK];
    #pragma unroll
    for (int j = 0; j < TOPK; ++j) {
        u32 v = hk0[j]; int o = (int)(v & 63u);
        hd0[j] = unmono(v & ~63u);
        hix0[j] = ((o >> 4) << 8) + (wid << 5) + (((o >> 2) & 3) << 3) + (hl << 2) + (o & 3);
    }

    // ---- intra-wave merge (lane n <-> n+32)
    {
        float mo = __shfl_xor(m0, 32), so = __shfl_xor(s0, 32);
        float mn = fmaxf(m0, mo);
        s0 = s0 * exp2f(m0 - mn) + so * exp2f(mo - mn);
        m0 = mn;
        float od[TOPK]; int oi[TOPK];
        #pragma unroll
        for (int j = 0; j < TOPK; ++j) {
            od[j] = __shfl_xor(hd0[j], 32); oi[j] = __shfl_xor(hix0[j], 32);
        }
        MERGE8(hd0, hix0, od, oi)
    }

    // ---- publish the 8 wave-lists per row
    __syncthreads();
    if (lane < 32) {
        const int base = arow * 64 + wid * 8;
        #pragma unroll
        for (int j = 0; j < TOPK; ++j) { pd[base + j] = hd0[j]; pi[base + j] = hix0[j]; }
        pm[arow * 8 + wid] = m0; ps[arow * 8 + wid] = s0;
    }
    __syncthreads();

    // ---- final merge (8 threads/row) -> seli/selm/sels (LDS) + ws_sel
    if (t < 256) {
        const int row = t >> 3, src = t & 7;
        float hd[TOPK]; int hix[TOPK];
        #pragma unroll
        for (int j = 0; j < TOPK; ++j) {
            hd[j] = pd[row * 64 + src * 8 + j];
            hix[j] = pi[row * 64 + src * 8 + j];
        }
        float m = pm[row * 8 + src], s = ps[row * 8 + src];
        #pragma unroll
        for (int k = 1; k <= 4; k <<= 1) {
            float mo = __shfl_xor(m, k), so = __shfl_xor(s, k);
            float mn = fmaxf(m, mo);
            s = s * exp2f(m - mn) + so * exp2f(mo - mn);
            m = mn;
            float od[TOPK]; int oi[TOPK];
            #pragma unroll
            for (int j = 0; j < TOPK; ++j) {
                od[j] = __shfl_xor(hd[j], k); oi[j] = __shfl_xor(hix[j], k);
            }
            MERGE8(hd, hix, od, oi)
        }
        if (src == 0) {
            size_t n = (size_t)(n0 + row);
            selm[row] = m;
            sels[row] = 1.0f / s;
            #pragma unroll
            for (int j = 0; j < TOPK; ++j) seli[row * 8 + j] = hix[j];
            *(int4*)(ws_sel + n * 8)     = make_int4(hix[0], hix[1], hix[2], hix[3]);
            *(int4*)(ws_sel + n * 8 + 4) = make_int4(hix[4], hix[5], hix[6], hix[7]);
        }
    }
    __syncthreads();

    // ---- recompute winner logits from LDS xh (true x_flat rows) + fp32 W, b
    {
        const int row = t >> 4, j = (t >> 1) & 7, half = t & 1;
        const int idxw = seli[row * 8 + j];
        const float4* wp = (const float4*)(Wm + ((size_t)idxw << 8)) + half * 32;
        float ax = 0.f, ay = 0.f, az = 0.f, aw2 = 0.f;
        #pragma unroll 8
        for (int i = 0; i < 16; ++i) {
            const int byte = ((half * 16 + i) * 32 + row) * 16;  // fragment-linear
            uint4 H = *(const uint4*)((const char*)xh + byte);
            float4 w0 = wp[i * 2], w1 = wp[i * 2 + 1];
            ax += bf2f((u16)H.x) * w0.x; ay += hi2f(H.x) * w0.y;
            az += bf2f((u16)H.y) * w0.z; aw2 += hi2f(H.y) * w0.w;
            ax += bf2f((u16)H.z) * w1.x; ay += hi2f(H.z) * w1.y;
            az += bf2f((u16)H.w) * w1.z; aw2 += hi2f(H.w) * w1.w;
        }
        float a = (ax + ay) + (az + aw2);
        a += __shfl_xor(a, 1);
        if (half == 0) {
            float p = exp2f((a + bv[idxw]) * L2E - selm[row]) * sels[row];
            ws_selp[(size_t)(n0 + row) * 8 + j] = p;
        }
    }
}

// ---------------- K2c: counts via LDS histogram (skew-proof) ----------------
__global__ __launch_bounds__(256)
void dl_count(const int* __restrict__ ws_sel, int* __restrict__ counts)
{
    __shared__ int hist[KDIM];
    const int t = threadIdx.x;
    #pragma unroll
    for (int i = 0; i < 4; ++i) hist[t + i * 256] = 0;
    __syncthreads();
    const int4* src = (const int4*)(ws_sel + (size_t)blockIdx.x * 8192);
    #pragma unroll
    for (int i = 0; i < 8; ++i) {
        int4 v = src[(size_t)i * 256 + t];
        atomicAdd(&hist[v.x], 1); atomicAdd(&hist[v.y], 1);
        atomicAdd(&hist[v.z], 1); atomicAdd(&hist[v.w], 1);
    }
    __syncthreads();
    #pragma unroll
    for (int i = 0; i < 4; ++i) {
        int k = t + i * 256;
        int c = hist[k];
        if (c) atomicAdd(&counts[k], c);
    }
}

// ---------------- K2: merged tail — rep compose + recon + MSE + partials ----
__global__ __launch_bounds__(256, 8)
void dl_tail(const float* __restrict__ x, const float* __restrict__ dict,
             const int* __restrict__ ws_sel, const float* __restrict__ ws_selp,
             float* __restrict__ out, float2* __restrict__ ws_lr)
{
    __shared__ float redL[4], redR[4];
    const int t = threadIdx.x;
    const int row = t >> 5, lr = t & 31;
    const size_t n = (size_t)blockIdx.x * 8 + row;

    int4 i0 = *(const int4*)(ws_sel + n * 8);
    int4 i1 = *(const int4*)(ws_sel + n * 8 + 4);
    const int idxs[8] = {i0.x, i0.y, i0.z, i0.w, i1.x, i1.y, i1.z, i1.w};
    float4 p0 = *(const float4*)(ws_selp + n * 8);
    float4 p1 = *(const float4*)(ws_selp + n * 8 + 4);
    const float p[8] = {p0.x, p0.y, p0.z, p0.w, p1.x, p1.y, p1.z, p1.w};

    // rep row: register-composed dense float4s, coalesced nt stores (8/thread)
    float* rr = out + 2 + (size_t)NELEM + (n << 10);
    #pragma unroll
    for (int q = 0; q < 8; ++q) {
        const int c0 = (q * 32 + lr) * 4;
        f32x4 v = {0.f, 0.f, 0.f, 0.f};
        #pragma unroll
        for (int j = 0; j < 8; ++j) {
            const int d = idxs[j] - c0;
            v[0] = (d == 0) ? p[j] : v[0];
            v[1] = (d == 1) ? p[j] : v[1];
            v[2] = (d == 2) ? p[j] : v[2];
            v[3] = (d == 3) ? p[j] : v[3];
        }
        __builtin_nontemporal_store(v, (f32x4*)(rr + c0));
    }

    // recon + fused MSE (flat .view semantics: raw-order x is correct here)
    float4 z4 = make_float4(0.f, 0.f, 0.f, 0.f);
    const float4* xp = (const float4*)(x + (n << 8)) + lr * 2;
    float4 xA = xp[0], xB = xp[1];
    float4 aA = z4, aB = z4;
    #pragma unroll
    for (int j = 0; j < 8; ++j) {
        const float4* dp = (const float4*)(dict + ((size_t)idxs[j] << 8)) + lr * 2;
        float4 dA = dp[0], dB = dp[1];
        aA.x += p[j] * dA.x; aA.y += p[j] * dA.y;
        aA.z += p[j] * dA.z; aA.w += p[j] * dA.w;
        aB.x += p[j] * dB.x; aB.y += p[j] * dB.y;
        aB.z += p[j] * dB.z; aB.w += p[j] * dB.w;
    }
    float* ro = out + 1 + (n << 8) + lr * 8;
    __builtin_nontemporal_store(__builtin_bit_cast(f32x4, aA), (f32x4*)ro);
    __builtin_nontemporal_store(__builtin_bit_cast(f32x4, aB), (f32x4*)(ro + 4));
    float e0 = xA.x - aA.x, e1 = xA.y - aA.y, e2 = xA.z - aA.z, e3 = xA.w - aA.w;
    float e4 = xB.x - aB.x, e5 = xB.y - aB.y, e6 = xB.z - aB.z, e7 = xB.w - aB.w;
    float lsum = ((e0*e0 + e1*e1) + (e2*e2 + e3*e3))
               + ((e4*e4 + e5*e5) + (e6*e6 + e7*e7));
    float rsum = 0.f;
    if (lr == 0) {
        #pragma unroll
        for (int j = 0; j < 8; ++j) rsum += p[j];
    }

    #pragma unroll
    for (int off = 32; off; off >>= 1) {
        lsum += __shfl_down(lsum, off);
        rsum += __shfl_down(rsum, off);
    }
    if ((t & 63) == 0) { redL[t >> 6] = lsum; redR[t >> 6] = rsum; }
    __syncthreads();
    if (t == 0) {
        ws_lr[blockIdx.x] = make_float2(
            (redL[0] + redL[1]) + (redL[2] + redL[3]),
            (redR[0] + redR[1]) + (redR[2] + redR[3]));
    }
}

// ---------------- finalize scalars ------------------------------------------
__global__ void dl_final(const float2* __restrict__ ws_lr,
                         const int* __restrict__ counts,
                         float* __restrict__ out)
{
    __shared__ float re[4], rl[4], rr[4];
    int t = threadIdx.x;
    float e = 0.f;
    for (int k = t; k < KDIM; k += 256) {
        float p = (float)counts[k] * (1.0f / 524288.0f);
        e += p * logf(p + 1e-10f);
    }
    float ls = 0.f, rs = 0.f;
    for (int i = t; i < 8192; i += 256) {
        float2 v = ws_lr[i];
        ls += v.x; rs += v.y;
    }
    #pragma unroll
    for (int off = 32; off; off >>= 1) {
        e += __shfl_down(e, off);
        ls += __shfl_down(ls, off);
        rs += __shfl_down(rs, off);
    }
    if ((t & 63) == 0) { re[t >> 6] = e; rl[t >> 6] = ls; rr[t >> 6] = rs; }
    __syncthreads();
    if (t == 0) {
        float et = (re[0] + re[1]) + (re[2] + re[3]);
        out[(size_t)NELEM + 1] = __expf(-et);                     // perplexity
        out[0] = 2.0f * ((rl[0] + rl[1]) + (rl[2] + rl[3])) / (float)NELEM
               + ((rr[0] + rr[1]) + (rr[2] + rr[3]));             // loss + reg
    }
}

extern "C" void kernel_launch(void* const* d_in, const int* in_sizes, int n_in,
                              void* d_out, int out_size, void* d_ws, size_t ws_size,
                              hipStream_t stream) {
    const float* x    = (const float*)d_in[0];
    const float* dict = (const float*)d_in[1];
    const float* Wm   = (const float*)d_in[2];
    const float* bv   = (const float*)d_in[3];
    float* out = (float*)d_out;

    int*    counts  = (int*)((char*)d_ws + WS_COUNTS);
    float*  dn      = (float*)((char*)d_ws + WS_DN);
    float*  b2      = (float*)((char*)d_ws + WS_B2);
    u16*    WhT     = (u16*)((char*)d_ws + WS_WH);
    u16*    DhT     = (u16*)((char*)d_ws + WS_DH);
    int*    ws_sel  = (int*)((char*)d_ws + WS_SEL);
    float*  ws_selp = (float*)((char*)d_ws + WS_SELP);
    float2* ws_lr   = (float2*)((char*)d_ws + WS_LR);

    hipMemsetAsync(d_ws, 0, 4608, stream);
    dl_prep<<<KDIM, 256, 0, stream>>>(Wm, dict, bv, WhT, DhT, dn, b2);
    dl_main<<<65536 / MROWS, 512, 0, stream>>>(x, Wm, bv, WhT, DhT, dn, b2,
                                               ws_sel, ws_selp);
    dl_count<<<64, 256, 0, stream>>>(ws_sel, counts);
    dl_tail<<<65536 / 8, 256, 0, stream>>>(x, dict, ws_sel, ws_selp, out, ws_lr);
    dl_final<<<1, 256, 0, stream>>>(ws_lr, counts, out);
}

// Round 21
// 289.588 us; speedup vs baseline: 1.2094x; 1.0012x over previous
//
#include <hip/hip_runtime.h>
#include <math.h>

#define CDIM 256
#define KDIM 1024
#define TOPK 8
#define MROWS 32
#define NELEM 16777216
#define L2E 1.4426950408889634f

typedef unsigned short u16;
typedef unsigned int u32;
typedef __attribute__((ext_vector_type(8))) short s16x8;
typedef __attribute__((ext_vector_type(8))) __bf16 b16x8;
typedef __attribute__((ext_vector_type(16))) float f32x16;
typedef __attribute__((ext_vector_type(4))) float f32x4;

#define ZERO16 {0.f,0.f,0.f,0.f,0.f,0.f,0.f,0.f,0.f,0.f,0.f,0.f,0.f,0.f,0.f,0.f}

// ws layout (bytes)
#define WS_COUNTS 64
#define WS_DN     4608
#define WS_B2     8704
#define WS_WH     16384                     // WhT: fragment-transposed, 512KB
#define WS_DH     (WS_WH + 524288)          // DhT: fragment-transposed, 512KB
#define WS_SEL    1064960                   // int[65536*8]   = 2 MB
#define WS_SELP   (WS_SEL + 2097152)        // float[65536*8] = 2 MB
#define WS_LR     (WS_SELP + 2097152)       // float2[8192]   = 64 KB

// K1 smem layout (bytes). xh FRAGMENT-LINEAR: fragment f of row r at byte
// (f*32+r)*16, dims [8f,8f+8). [16K,32K) is merge-overlay scratch only.
#define SM_XH   0        // 16K (LIVE through p-recompute)
#define SM_B2   32768    // 4K
#define SM_DN   36864    // 4K
#define SM_TOT  40960
#define SM_PD   16384    // 8K scratch
#define SM_PI   24576    // 8K scratch
#define SM_PM   32768    // 1K over b2
#define SM_PS   33792    // 1K over b2
#define SM_SELI 36864    // 1K over dn
#define SM_SELM 37888    // 128B over dn
#define SM_SELS 38016    // 128B over dn

__device__ __forceinline__ u16 f2bf(float f) {
    u32 u = __builtin_bit_cast(u32, f);
    u += 0x7FFFu + ((u >> 16) & 1u);
    return (u16)(u >> 16);
}
__device__ __forceinline__ float bf2f(u16 h) {
    return __builtin_bit_cast(float, ((u32)h) << 16);
}
__device__ __forceinline__ float hi2f(u32 u) {
    return __builtin_bit_cast(float, u & 0xFFFF0000u);
}
__device__ __forceinline__ f32x16 mfma16(s16x8 a, s16x8 b, f32x16 c) {
    return __builtin_amdgcn_mfma_f32_32x32x16_bf16(
        __builtin_bit_cast(b16x8, a), __builtin_bit_cast(b16x8, b), c, 0, 0, 0);
}
__device__ __forceinline__ u32 mono(float f) {
    u32 u = __builtin_bit_cast(u32, f);
    int m = (int)u >> 31;
    return u ^ (u32)(m | (int)0x80000000);
}
__device__ __forceinline__ float unmono(u32 v) {
    int m = (int)v >> 31;
    return __builtin_bit_cast(float, v ^ (u32)((int)0x80000000 | ~m));
}

// compare-exchange on packed u32 keys: v_min_u32 + v_max_u32
#define CEK(K, A, B) { u32 lo_ = min(K[A], K[B]); u32 hi_ = max(K[A], K[B]); \
                       K[A] = lo_; K[B] = hi_; }

// 4-wide batch insert: sort c[0..3], then bitonic-merge into sorted hk[0..7].
#define MERGE4(HK, C) { \
    CEK(C,0,1) CEK(C,2,3) CEK(C,0,2) CEK(C,1,3) CEK(C,1,2) \
    HK[4] = min(HK[4], C[3]); HK[5] = min(HK[5], C[2]); \
    HK[6] = min(HK[6], C[1]); HK[7] = min(HK[7], C[0]); \
    CEK(HK,0,4) CEK(HK,1,5) CEK(HK,2,6) CEK(HK,3,7) \
    CEK(HK,0,2) CEK(HK,1,3) CEK(HK,4,6) CEK(HK,5,7) \
    CEK(HK,0,1) CEK(HK,2,3) CEK(HK,4,5) CEK(HK,6,7) }

#define CE(HD, HX, A, B) { \
    bool sw_ = (HD[B] < HD[A]) || (HD[B] == HD[A] && HX[B] < HX[A]); \
    if (sw_) { float td_ = HD[A]; HD[A] = HD[B]; HD[B] = td_; \
               int ti_ = HX[A]; HX[A] = HX[B]; HX[B] = ti_; } }

#define MERGE8(HD, HX, OD, OI) { \
    _Pragma("unroll") \
    for (int j_ = 0; j_ < 8; ++j_) { \
        float bd_ = OD[7 - j_]; int bi_ = OI[7 - j_]; \
        if (bd_ < HD[j_] || (bd_ == HD[j_] && bi_ < HX[j_])) { \
            HD[j_] = bd_; HX[j_] = bi_; } } \
    CE(HD,HX,0,4) CE(HD,HX,1,5) CE(HD,HX,2,6) CE(HD,HX,3,7) \
    CE(HD,HX,0,2) CE(HD,HX,1,3) CE(HD,HX,4,6) CE(HD,HX,5,7) \
    CE(HD,HX,0,1) CE(HD,HX,2,3) CE(HD,HX,4,5) CE(HD,HX,6,7) }

#define SMAX_TILE(ACC, MM, SS) { \
    float lv_[16]; \
    _Pragma("unroll") \
    for (int rg_ = 0; rg_ < 4; ++rg_) { \
        lv_[4*rg_+0] = ACC[4*rg_+0] + bv4[rg_].x; \
        lv_[4*rg_+1] = ACC[4*rg_+1] + bv4[rg_].y; \
        lv_[4*rg_+2] = ACC[4*rg_+2] + bv4[rg_].z; \
        lv_[4*rg_+3] = ACC[4*rg_+3] + bv4[rg_].w; } \
    float x0_ = fmaxf(lv_[0],lv_[1]),  x1_ = fmaxf(lv_[2],lv_[3]); \
    float x2_ = fmaxf(lv_[4],lv_[5]),  x3_ = fmaxf(lv_[6],lv_[7]); \
    float x4_ = fmaxf(lv_[8],lv_[9]),  x5_ = fmaxf(lv_[10],lv_[11]); \
    float x6_ = fmaxf(lv_[12],lv_[13]), x7_ = fmaxf(lv_[14],lv_[15]); \
    x0_ = fmaxf(x0_,x1_); x2_ = fmaxf(x2_,x3_); \
    x4_ = fmaxf(x4_,x5_); x6_ = fmaxf(x6_,x7_); \
    float mn_ = fmaxf(fmaxf(fmaxf(x0_,x2_), fmaxf(x4_,x6_)), MM); \
    float e0_ = exp2f(lv_[0]-mn_) + exp2f(lv_[1]-mn_); \
    float e1_ = exp2f(lv_[2]-mn_) + exp2f(lv_[3]-mn_); \
    float e2_ = exp2f(lv_[4]-mn_) + exp2f(lv_[5]-mn_); \
    float e3_ = exp2f(lv_[6]-mn_) + exp2f(lv_[7]-mn_); \
    float e4_ = exp2f(lv_[8]-mn_) + exp2f(lv_[9]-mn_); \
    float e5_ = exp2f(lv_[10]-mn_) + exp2f(lv_[11]-mn_); \
    float e6_ = exp2f(lv_[12]-mn_) + exp2f(lv_[13]-mn_); \
    float e7_ = exp2f(lv_[14]-mn_) + exp2f(lv_[15]-mn_); \
    float sa_ = ((e0_+e1_) + (e2_+e3_)) + ((e4_+e5_) + (e6_+e7_)); \
    SS = SS * exp2f(MM - mn_) + sa_; MM = mn_; }

// ---------------- prepass: bf16 splits into FRAGMENT-TRANSPOSED layout ------
__global__ __launch_bounds__(256)
void dl_prep(const float* __restrict__ Wm, const float* __restrict__ dict,
             const float* __restrict__ bv,
             u16* __restrict__ WhT, u16* __restrict__ DhT,
             float* __restrict__ dn, float* __restrict__ b2)
{
    __shared__ float red[4];
    const int k = blockIdx.x, c = threadIdx.x;
    const size_t idx = ((size_t)k << 8) + c;
    const size_t dst = ((((size_t)(k >> 5) * 16 + (c >> 4)) * 64)
                        + (((c >> 3) & 1) << 5) + (k & 31)) * 8 + (c & 7);
    WhT[dst] = f2bf(Wm[idx] * L2E);
    float d = dict[idx];
    DhT[dst] = f2bf(-2.0f * d);
    float sq = d * d;
    #pragma unroll
    for (int off = 32; off; off >>= 1) sq += __shfl_down(sq, off);
    if ((c & 63) == 0) red[c >> 6] = sq;
    __syncthreads();
    if (c == 0) { dn[k] = red[0] + red[1] + red[2] + red[3]; b2[k] = bv[k] * L2E; }
}

// ---------------- K1: selection + probabilities (unroll 4 merged loop) ------
__global__ __launch_bounds__(512, 6)
void dl_main(const float* __restrict__ x, const float* __restrict__ Wm,
             const float* __restrict__ bv, const u16* __restrict__ WhT,
             const u16* __restrict__ DhT, const float* __restrict__ dnp,
             const float* __restrict__ b2g,
             int* __restrict__ ws_sel, float* __restrict__ ws_selp)
{
    __shared__ __align__(16) char smem[SM_TOT];
    u16*   xh   = (u16*)(smem + SM_XH);
    float* b2_s = (float*)(smem + SM_B2);
    float* dn_s = (float*)(smem + SM_DN);
    float* pd   = (float*)(smem + SM_PD);
    int*   pi   = (int*)(smem + SM_PI);
    float* pm   = (float*)(smem + SM_PM);
    float* ps   = (float*)(smem + SM_PS);
    int*   seli = (int*)(smem + SM_SELI);
    float* selm = (float*)(smem + SM_SELM);
    float* sels = (float*)(smem + SM_SELS);

    const int t = threadIdx.x;
    const int lane = t & 63;
    const int wid = t >> 6;
    const int n0 = blockIdx.x * MROWS;

    // ---- stage x -> bf16 hi in FRAGMENT-LINEAR layout (write addr = t*16)
    {
        const int r = t & 31;
        const float* xb = x + ((size_t)(n0 >> 12) << 20) + (n0 & 4095) + r;
        #pragma unroll
        for (int gg = 0; gg < 2; ++gg) {
            const int f = (t >> 5) + gg * 16;     // fragment id, dims [8f,8f+8)
            const int c0 = f * 8;
            u32 hw[4];
            #pragma unroll
            for (int i = 0; i < 8; i += 2) {
                float a0 = xb[(size_t)(c0 + i) << 12];
                float a1 = xb[(size_t)(c0 + i + 1) << 12];
                hw[i >> 1] = (u32)f2bf(a0) | ((u32)f2bf(a1) << 16);
            }
            const int byte = (f * 32 + r) * 16;   // == (t + gg*512)*16, linear
            *(uint4*)((char*)xh + byte) = make_uint4(hw[0], hw[1], hw[2], hw[3]);
        }
        b2_s[t] = b2g[t];  b2_s[512 + t] = b2g[512 + t];
        dn_s[t] = dnp[t];  dn_s[512 + t] = dnp[512 + t];
    }
    __syncthreads();

    const int arow = lane & 31, hl = lane >> 5;

    float m0 = -INFINITY, s0 = 0.f;
    u32 hk0[TOPK];
    #pragma unroll
    for (int j = 0; j < TOPK; ++j) hk0[j] = 0xFFFFFFFFu;

    // ---- barrier-free main loop: 4 chunks of 256 atoms, single merged phase,
    //      unroll 4 (8 global + 4 LDS loads in flight per wait)
    #pragma unroll 1
    for (int ck = 0; ck < 4; ++ck) {
        const int ab = ck * 8 + wid;          // atom block: atoms [ab*32, +32)
        const u16* Wp = WhT + ((size_t)ab << 13) + (lane << 3);
        const u16* Dp = DhT + ((size_t)ab << 13) + (lane << 3);
        const int cb = (ck << 8) + (wid << 5) + (hl << 2);

        f32x16 accL = ZERO16, accD = ZERO16;
        __builtin_amdgcn_s_setprio(1);
        #pragma unroll 4
        for (int kst = 0; kst < 16; ++kst) {
            int bo = kst * 1024 + lane * 16;
            s16x8 aw  = *(const s16x8*)(Wp + kst * 512);
            s16x8 adh = *(const s16x8*)(Dp + kst * 512);
            s16x8 bh = *(const s16x8*)((const char*)xh + bo);
            accL = mfma16(aw,  bh, accL);
            accD = mfma16(adh, bh, accD);
        }
        __builtin_amdgcn_s_setprio(0);

        float4 bv4[4];
        #pragma unroll
        for (int rg = 0; rg < 4; ++rg)
            bv4[rg] = *(const float4*)(b2_s + cb + rg * 8);
        SMAX_TILE(accL, m0, s0)

        float4 n44[4];
        #pragma unroll
        for (int rg = 0; rg < 4; ++rg)
            n44[rg] = *(const float4*)(dn_s + cb + rg * 8);
        const u32 ob = (u32)(ck << 4);
        #pragma unroll
        for (int rg = 0; rg < 4; ++rg) {
            const u32 o0 = ob + rg * 4;
            u32 c[4];
            c[0] = (mono(n44[rg].x + accD[4*rg+0]) & ~63u) | (o0 + 0);
            c[1] = (mono(n44[rg].y + accD[4*rg+1]) & ~63u) | (o0 + 1);
            c[2] = (mono(n44[rg].z + accD[4*rg+2]) & ~63u) | (o0 + 2);
            c[3] = (mono(n44[rg].w + accD[4*rg+3]) & ~63u) | (o0 + 3);
            MERGE4(hk0, c)
        }
    }

    // ---- decode packed keys -> (dist, global atom idx)
    float hd0[TOPK];
    int hix0[TOPK];
    #pragma unroll
    for (int j = 0; j < TOPK; ++j) {
        u32 v = hk0[j]; int o = (int)(v & 63u);
        hd0[j] = unmono(v & ~63u);
        hix0[j] = ((o >> 4) << 8) + (wid << 5) + (((o >> 2) & 3) << 3) + (hl << 2) + (o & 3);
    }

    // ---- intra-wave merge (lane n <-> n+32)
    {
        float mo = __shfl_xor(m0, 32), so = __shfl_xor(s0, 32);
        float mn = fmaxf(m0, mo);
        s0 = s0 * exp2f(m0 - mn) + so * exp2f(mo - mn);
        m0 = mn;
        float od[TOPK]; int oi[TOPK];
        #pragma unroll
        for (int j = 0; j < TOPK; ++j) {
            od[j] = __shfl_xor(hd0[j], 32); oi[j] = __shfl_xor(hix0[j], 32);
        }
        MERGE8(hd0, hix0, od, oi)
    }

    // ---- publish the 8 wave-lists per row
    __syncthreads();
    if (lane < 32) {
        const int base = arow * 64 + wid * 8;
        #pragma unroll
        for (int j = 0; j < TOPK; ++j) { pd[base + j] = hd0[j]; pi[base + j] = hix0[j]; }
        pm[arow * 8 + wid] = m0; ps[arow * 8 + wid] = s0;
    }
    __syncthreads();

    // ---- final merge (8 threads/row) -> seli/selm/sels (LDS) + ws_sel
    if (t < 256) {
        const int row = t >> 3, src = t & 7;
        float hd[TOPK]; int hix[TOPK];
        #pragma unroll
        for (int j = 0; j < TOPK; ++j) {
            hd[j] = pd[row * 64 + src * 8 + j];
            hix[j] = pi[row * 64 + src * 8 + j];
        }
        float m = pm[row * 8 + src], s = ps[row * 8 + src];
        #pragma unroll
        for (int k = 1; k <= 4; k <<= 1) {
            float mo = __shfl_xor(m, k), so = __shfl_xor(s, k);
            float mn = fmaxf(m, mo);
            s = s * exp2f(m - mn) + so * exp2f(mo - mn);
            m = mn;
            float od[TOPK]; int oi[TOPK];
            #pragma unroll
            for (int j = 0; j < TOPK; ++j) {
                od[j] = __shfl_xor(hd[j], k); oi[j] = __shfl_xor(hix[j], k);
            }
            MERGE8(hd, hix, od, oi)
        }
        if (src == 0) {
            size_t n = (size_t)(n0 + row);
            selm[row] = m;
            sels[row] = 1.0f / s;
            #pragma unroll
            for (int j = 0; j < TOPK; ++j) seli[row * 8 + j] = hix[j];
            *(int4*)(ws_sel + n * 8)     = make_int4(hix[0], hix[1], hix[2], hix[3]);
            *(int4*)(ws_sel + n * 8 + 4) = make_int4(hix[4], hix[5], hix[6], hix[7]);
        }
    }
    __syncthreads();

    // ---- recompute winner logits from LDS xh (true x_flat rows) + fp32 W, b
    {
        const int row = t >> 4, j = (t >> 1) & 7, half = t & 1;
        const int idxw = seli[row * 8 + j];
        const float4* wp = (const float4*)(Wm + ((size_t)idxw << 8)) + half * 32;
        float ax = 0.f, ay = 0.f, az = 0.f, aw2 = 0.f;
        #pragma unroll 8
        for (int i = 0; i < 16; ++i) {
            const int byte = ((half * 16 + i) * 32 + row) * 16;  // fragment-linear
            uint4 H = *(const uint4*)((const char*)xh + byte);
            float4 w0 = wp[i * 2], w1 = wp[i * 2 + 1];
            ax += bf2f((u16)H.x) * w0.x; ay += hi2f(H.x) * w0.y;
            az += bf2f((u16)H.y) * w0.z; aw2 += hi2f(H.y) * w0.w;
            ax += bf2f((u16)H.z) * w1.x; ay += hi2f(H.z) * w1.y;
            az += bf2f((u16)H.w) * w1.z; aw2 += hi2f(H.w) * w1.w;
        }
        float a = (ax + ay) + (az + aw2);
        a += __shfl_xor(a, 1);
        if (half == 0) {
            float p = exp2f((a + bv[idxw]) * L2E - selm[row]) * sels[row];
            ws_selp[(size_t)(n0 + row) * 8 + j] = p;
        }
    }
}

// ---------------- K2c: counts via LDS histogram (skew-proof) ----------------
__global__ __launch_bounds__(256)
void dl_count(const int* __restrict__ ws_sel, int* __restrict__ counts)
{
    __shared__ int hist[KDIM];
    const int t = threadIdx.x;
    #pragma unroll
    for (int i = 0; i < 4; ++i) hist[t + i * 256] = 0;
    __syncthreads();
    const int4* src = (const int4*)(ws_sel + (size_t)blockIdx.x * 8192);
    #pragma unroll
    for (int i = 0; i < 8; ++i) {
        int4 v = src[(size_t)i * 256 + t];
        atomicAdd(&hist[v.x], 1); atomicAdd(&hist[v.y], 1);
        atomicAdd(&hist[v.z], 1); atomicAdd(&hist[v.w], 1);
    }
    __syncthreads();
    #pragma unroll
    for (int i = 0; i < 4; ++i) {
        int k = t + i * 256;
        int c = hist[k];
        if (c) atomicAdd(&counts[k], c);
    }
}

// ---------------- K2: merged tail — rep compose + recon + MSE + partials ----
__global__ __launch_bounds__(256, 8)
void dl_tail(const float* __restrict__ x, const float* __restrict__ dict,
             const int* __restrict__ ws_sel, const float* __restrict__ ws_selp,
             float* __restrict__ out, float2* __restrict__ ws_lr)
{
    __shared__ float redL[4], redR[4];
    const int t = threadIdx.x;
    const int row = t >> 5, lr = t & 31;
    const size_t n = (size_t)blockIdx.x * 8 + row;

    int4 i0 = *(const int4*)(ws_sel + n * 8);
    int4 i1 = *(const int4*)(ws_sel + n * 8 + 4);
    const int idxs[8] = {i0.x, i0.y, i0.z, i0.w, i1.x, i1.y, i1.z, i1.w};
    float4 p0 = *(const float4*)(ws_selp + n * 8);
    float4 p1 = *(const float4*)(ws_selp + n * 8 + 4);
    const float p[8] = {p0.x, p0.y, p0.z, p0.w, p1.x, p1.y, p1.z, p1.w};

    // rep row: register-composed dense float4s, coalesced nt stores (8/thread)
    float* rr = out + 2 + (size_t)NELEM + (n << 10);
    #pragma unroll
    for (int q = 0; q < 8; ++q) {
        const int c0 = (q * 32 + lr) * 4;
        f32x4 v = {0.f, 0.f, 0.f, 0.f};
        #pragma unroll
        for (int j = 0; j < 8; ++j) {
            const int d = idxs[j] - c0;
            v[0] = (d == 0) ? p[j] : v[0];
            v[1] = (d == 1) ? p[j] : v[1];
            v[2] = (d == 2) ? p[j] : v[2];
            v[3] = (d == 3) ? p[j] : v[3];
        }
        __builtin_nontemporal_store(v, (f32x4*)(rr + c0));
    }

    // recon + fused MSE (flat .view semantics: raw-order x is correct here)
    float4 z4 = make_float4(0.f, 0.f, 0.f, 0.f);
    const float4* xp = (const float4*)(x + (n << 8)) + lr * 2;
    float4 xA = xp[0], xB = xp[1];
    float4 aA = z4, aB = z4;
    #pragma unroll
    for (int j = 0; j < 8; ++j) {
        const float4* dp = (const float4*)(dict + ((size_t)idxs[j] << 8)) + lr * 2;
        float4 dA = dp[0], dB = dp[1];
        aA.x += p[j] * dA.x; aA.y += p[j] * dA.y;
        aA.z += p[j] * dA.z; aA.w += p[j] * dA.w;
        aB.x += p[j] * dB.x; aB.y += p[j] * dB.y;
        aB.z += p[j] * dB.z; aB.w += p[j] * dB.w;
    }
    float* ro = out + 1 + (n << 8) + lr * 8;
    __builtin_nontemporal_store(__builtin_bit_cast(f32x4, aA), (f32x4*)ro);
    __builtin_nontemporal_store(__builtin_bit_cast(f32x4, aB), (f32x4*)(ro + 4));
    float e0 = xA.x - aA.x, e1 = xA.y - aA.y, e2 = xA.z - aA.z, e3 = xA.w - aA.w;
    float e4 = xB.x - aB.x, e5 = xB.y - aB.y, e6 = xB.z - aB.z, e7 = xB.w - aB.w;
    float lsum = ((e0*e0 + e1*e1) + (e2*e2 + e3*e3))
               + ((e4*e4 + e5*e5) + (e6*e6 + e7*e7));
    float rsum = 0.f;
    if (lr == 0) {
        #pragma unroll
        for (int j = 0; j < 8; ++j) rsum += p[j];
    }

    #pragma unroll
    for (int off = 32; off; off >>= 1) {
        lsum += __shfl_down(lsum, off);
        rsum += __shfl_down(rsum, off);
    }
    if ((t & 63) == 0) { redL[t >> 6] = lsum; redR[t >> 6] = rsum; }
    __syncthreads();
    if (t == 0) {
        ws_lr[blockIdx.x] = make_float2(
            (redL[0] + redL[1]) + (redL[2] + redL[3]),
            (redR[0] + redR[1]) + (redR[2] + redR[3]));
    }
}

// ---------------- finalize scalars ------------------------------------------
__global__ void dl_final(const float2* __restrict__ ws_lr,
                         const int* __restrict__ counts,
                         float* __restrict__ out)
{
    __shared__ float re[4], rl[4], rr[4];
    int t = threadIdx.x;
    float e = 0.f;
    for (int k = t; k < KDIM; k += 256) {
        float p = (float)counts[k] * (1.0f / 524288.0f);
        e += p * logf(p + 1e-10f);
    }
    float ls = 0.f, rs = 0.f;
    for (int i = t; i < 8192; i += 256) {
        float2 v = ws_lr[i];
        ls += v.x; rs += v.y;
    }
    #pragma unroll
    for (int off = 32; off; off >>= 1) {
        e += __shfl_down(e, off);
        ls += __shfl_down(ls, off);
        rs += __shfl_down(rs, off);
    }
    if ((t & 63) == 0) { re[t >> 6] = e; rl[t >> 6] = ls; rr[t >> 6] = rs; }
    __syncthreads();
    if (t == 0) {
        float et = (re[0] + re[1]) + (re[2] + re[3]);
        out[(size_t)NELEM + 1] = __expf(-et);                     // perplexity
        out[0] = 2.0f * ((rl[0] + rl[1]) + (rl[2] + rl[3])) / (float)NELEM
               + ((rr[0] + rr[1]) + (rr[2] + rr[3]));             // loss + reg
    }
}

extern "C" void kernel_launch(void* const* d_in, const int* in_sizes, int n_in,
                              void* d_out, int out_size, void* d_ws, size_t ws_size,
                              hipStream_t stream) {
    const float* x    = (const float*)d_in[0];
    const float* dict = (const float*)d_in[1];
    const float* Wm   = (const float*)d_in[2];
    const float* bv   = (const float*)d_in[3];
    float* out = (float*)d_out;

    int*    counts  = (int*)((char*)d_ws + WS_COUNTS);
    float*  dn      = (float*)((char*)d_ws + WS_DN);
    float*  b2      = (float*)((char*)d_ws + WS_B2);
    u16*    WhT     = (u16*)((char*)d_ws + WS_WH);
    u16*    DhT     = (u16*)((char*)d_ws + WS_DH);
    int*    ws_sel  = (int*)((char*)d_ws + WS_SEL);
    float*  ws_selp = (float*)((char*)d_ws + WS_SELP);
    float2* ws_lr   = (float2*)((char*)d_ws + WS_LR);

    hipMemsetAsync(d_ws, 0, 4608, stream);
    dl_prep<<<KDIM, 256, 0, stream>>>(Wm, dict, bv, WhT, DhT, dn, b2);
    dl_main<<<65536 / MROWS, 512, 0, stream>>>(x, Wm, bv, WhT, DhT, dn, b2,
                                               ws_sel, ws_selp);
    dl_count<<<64, 256, 0, stream>>>(ws_sel, counts);
    dl_tail<<<65536 / 8, 256, 0, stream>>>(x, dict, ws_sel, ws_selp, out, ws_lr);
    dl_final<<<1, 256, 0, stream>>>(ws_lr, counts, out);
}